// Round 4
// baseline (691.284 us; speedup 1.0000x reference)
//
#include <hip/hip_runtime.h>
#include <cstdint>
#include <cstddef>

// ---------------- problem constants ----------------
constexpr int NNODES = 50000;
constexpr int NEDGES = 500000;
constexpr int NRELS  = 8;
constexpr int DIM    = 128;   // input/output dim
constexpr int ADIM   = 64;    // attention dim
constexpr int TWOD   = 256;   // 2*DIM
constexpr int EPB    = 64;    // edges per block in gate kernel
constexpr float SLOPE = 0.01f; // leaky_relu default slope

constexpr int XPITCH = TWOD + 8;   // LDS row pitch (bf16 elems) for K=256 kernels
constexpr int PPITCH = DIM + 8;    // LDS row pitch for K=128 kernel
constexpr int MPITCH = DIM + 8;    // msg LDS pitch: 136 -> 16B-aligned rows, quad writes 2-way max

typedef __attribute__((ext_vector_type(8))) short short8;   // 8 bf16 = 4 VGPRs (MFMA A/B frag)
typedef __attribute__((ext_vector_type(4))) float floatx4;  // MFMA C/D frag

// fp32 -> bf16 round-to-nearest-even
__device__ __forceinline__ unsigned short f2bf(float f) {
    unsigned u = __float_as_uint(f);
    unsigned r = u + 0x7FFFu + ((u >> 16) & 1u);
    return (unsigned short)(r >> 16);
}
__device__ __forceinline__ float bf2f(unsigned short b) {
    return __uint_as_float(((unsigned)b) << 16);
}

// monotone float->uint encoding for atomicMax on floats
__device__ __forceinline__ unsigned enc_f(float f) {
    unsigned u = __float_as_uint(f);
    return (u & 0x80000000u) ? ~u : (u | 0x80000000u);
}
__device__ __forceinline__ float dec_f(unsigned k) {
    unsigned u = (k & 0x80000000u) ? (k & 0x7FFFFFFFu) : ~k;
    return __uint_as_float(u);
}

// ---------------- init ----------------
__global__ void k_init(float* __restrict__ hN, float* __restrict__ denom,
                       unsigned* __restrict__ smax_u, int* __restrict__ sorted,
                       int* __restrict__ cnts /*16 ints*/,
                       int* __restrict__ histD, int* __restrict__ cursorD) {
    int i = blockIdx.x * blockDim.x + threadIdx.x;
    int stride = gridDim.x * blockDim.x;
    for (int idx = i; idx < NNODES * DIM; idx += stride) hN[idx] = 0.0f;
    for (int idx = i; idx < NNODES; idx += stride) {
        denom[idx] = 0.0f; smax_u[idx] = 0u;
        if (histD) { histD[idx] = 0; cursorD[idx] = 0; }
    }
    for (int idx = i; idx < NEDGES + 1024; idx += stride) sorted[idx] = -1;
    if (i < 16) cnts[i] = 0;
}

// ---------------- prep: bf16 weight tables ----------------
__global__ void k_prep(const float* __restrict__ rel, const float* __restrict__ W_lin,
                       const float* __restrict__ W_a,
                       unsigned short* __restrict__ relT, unsigned short* __restrict__ Wl,
                       unsigned short* __restrict__ Wa2) {
    int idx = blockIdx.x * 256 + threadIdx.x;
    const int NREL_ELEMS = NRELS * TWOD * DIM;  // 262144
    const int WL_ELEMS = DIM * TWOD;            // 32768
    const int WA2_ELEMS = DIM * DIM;            // 16384
    if (idx < NREL_ELEMS) {
        int d = idx & 255;
        int o = (idx >> 8) & 127;
        int r = idx >> 15;
        relT[((size_t)r * DIM + o) * TWOD + d] = f2bf(rel[((size_t)r * TWOD + d) * DIM + o]);
    } else if (idx < NREL_ELEMS + WL_ELEMS) {
        int j = idx - NREL_ELEMS;
        Wl[j] = f2bf(W_lin[j]);
    } else if (idx < NREL_ELEMS + WL_ELEMS + WA2_ELEMS) {
        int j = idx - NREL_ELEMS - WL_ELEMS;
        int d = j & 127, o = j >> 7;
        float v = (o < ADIM) ? W_a[(size_t)o * TWOD + d] : W_a[(size_t)(o - ADIM) * TWOD + DIM + d];
        Wa2[j] = f2bf(v);
    }
}

// ---------------- counting sort by etype ----------------
__global__ void k_count(const int* __restrict__ ety, int* __restrict__ cnt) {
    __shared__ int hist[NRELS];
    int t = threadIdx.x;
    if (t < NRELS) hist[t] = 0;
    __syncthreads();
    int e = blockIdx.x * 256 + t;
    if (e < NEDGES) atomicAdd(&hist[ety[e]], 1);
    __syncthreads();
    if (t < NRELS && hist[t] > 0) atomicAdd(&cnt[t], hist[t]);
}

__global__ void k_prefix(const int* __restrict__ cnt, int* __restrict__ offs) {
    if (blockIdx.x == 0 && threadIdx.x == 0) {
        int off = 0;
        for (int r = 0; r < NRELS; r++) {
            offs[r] = off;
            off += ((cnt[r] + EPB - 1) / EPB) * EPB;
        }
    }
}

__global__ void k_scatter(const int* __restrict__ ety, const int* __restrict__ offs,
                          int* __restrict__ cursor, int* __restrict__ sorted) {
    __shared__ int hist[NRELS];
    __shared__ int basew[NRELS];
    int t = threadIdx.x;
    if (t < NRELS) hist[t] = 0;
    __syncthreads();
    int e = blockIdx.x * 256 + t;
    int r = -1, rank = 0;
    if (e < NEDGES) { r = ety[e]; rank = atomicAdd(&hist[r], 1); }
    __syncthreads();
    if (t < NRELS && hist[t] > 0) basew[t] = atomicAdd(&cursor[t], hist[t]);
    __syncthreads();
    if (e < NEDGES) sorted[offs[r] + basew[r] + rank] = e;
}

// ---------------- dst-CSR build ----------------
__global__ void k_histD(const int* __restrict__ dst, int* __restrict__ histD) {
    int e = blockIdx.x * 256 + threadIdx.x;
    if (e < NEDGES) atomicAdd(&histD[dst[e]], 1);
}

__global__ __launch_bounds__(1024) void k_scanD(const int* __restrict__ histD,
                                                int* __restrict__ row_ptr) {
    __shared__ int ls[1024];
    const int t = threadIdx.x;
    const int CH = (NNODES + 1023) / 1024;  // 49
    const int base = t * CH;
    int s = 0;
    for (int j = 0; j < CH; j++) { int i = base + j; if (i < NNODES) s += histD[i]; }
    ls[t] = s;
    __syncthreads();
    // Hillis-Steele inclusive scan
    for (int off = 1; off < 1024; off <<= 1) {
        int v = (t >= off) ? ls[t - off] : 0;
        __syncthreads();
        ls[t] += v;
        __syncthreads();
    }
    int run = (t == 0) ? 0 : ls[t - 1];
    for (int j = 0; j < CH; j++) {
        int i = base + j;
        if (i < NNODES) { row_ptr[i] = run; run += histD[i]; }
    }
    if (t == 1023) row_ptr[NNODES] = ls[1023];
}

__global__ void k_dscatter(const int* __restrict__ dst, const int* __restrict__ row_ptr,
                           int* __restrict__ cursorD, int* __restrict__ dcsr) {
    int e = blockIdx.x * 256 + threadIdx.x;
    if (e < NEDGES) {
        int dn = dst[e];
        int pos = row_ptr[dn] + atomicAdd(&cursorD[dn], 1);
        dcsr[pos] = e;
    }
}

// ---------------- node attention projections via MFMA ----------------
__global__ __launch_bounds__(256) void k_nodeproj(const float* __restrict__ h,
                                                  const unsigned short* __restrict__ Wa2,
                                                  float* __restrict__ proj) {
    __shared__ unsigned short Xs[EPB * PPITCH];
    const int t = threadIdx.x;
    const int nb = blockIdx.x * 64;

#pragma unroll
    for (int u = 0; u < 4; u++) {
        int v = u * 256 + t;
        int i = v >> 4;
        int c = v & 15;
        int n = nb + i;
        if (n >= NNODES) n = NNODES - 1;
        const float4* hp = (const float4*)(h + (size_t)n * DIM + c * 8);
        float4 a = hp[0], b = hp[1];
        union { unsigned short us[8]; short8 s8; } pk;
        pk.us[0] = f2bf(a.x); pk.us[1] = f2bf(a.y); pk.us[2] = f2bf(a.z); pk.us[3] = f2bf(a.w);
        pk.us[4] = f2bf(b.x); pk.us[5] = f2bf(b.y); pk.us[6] = f2bf(b.z); pk.us[7] = f2bf(b.w);
        *(short8*)&Xs[i * PPITCH + c * 8] = pk.s8;
    }

    const int wave = t >> 6;
    const int lane = t & 63;
    const int q = lane >> 4;
    const int l16 = lane & 15;

    short8 Bf[2][4];
#pragma unroll
    for (int nn = 0; nn < 2; nn++) {
        int o = (wave * 2 + nn) * 16 + l16;
        const unsigned short* bp = Wa2 + (size_t)o * DIM + q * 8;
#pragma unroll
        for (int ks = 0; ks < 4; ks++) Bf[nn][ks] = *(const short8*)(bp + ks * 32);
    }

    __syncthreads();

    floatx4 acc[4][2];
#pragma unroll
    for (int m = 0; m < 4; m++)
#pragma unroll
        for (int nn = 0; nn < 2; nn++) acc[m][nn] = (floatx4)(0.0f);

#pragma unroll
    for (int ks = 0; ks < 4; ks++) {
        short8 Af[4];
        const unsigned short* xb = &Xs[l16 * PPITCH + ks * 32 + q * 8];
#pragma unroll
        for (int m = 0; m < 4; m++) Af[m] = *(const short8*)(xb + m * 16 * PPITCH);
#pragma unroll
        for (int m = 0; m < 4; m++)
#pragma unroll
            for (int nn = 0; nn < 2; nn++)
                acc[m][nn] = __builtin_amdgcn_mfma_f32_16x16x32_bf16(Af[m], Bf[nn][ks], acc[m][nn], 0, 0, 0);
    }

#pragma unroll
    for (int m = 0; m < 4; m++) {
        int ib = m * 16 + q * 4;
#pragma unroll
        for (int nn = 0; nn < 2; nn++) {
            int o = (wave * 2 + nn) * 16 + l16;
#pragma unroll
            for (int rg = 0; rg < 4; rg++) {
                int n = nb + ib + rg;
                if (n < NNODES) proj[(size_t)n * DIM + o] = acc[m][nn][rg];
            }
        }
    }
}

// ---------------- per-edge score + segment max (wave per edge) ----------------
__global__ __launch_bounds__(256) void k_score(const float* __restrict__ proj,
                                               const float* __restrict__ b_a, const float* __restrict__ ratt,
                                               const int* __restrict__ src, const int* __restrict__ dst,
                                               float* __restrict__ score, unsigned* __restrict__ smax_u) {
    int e = blockIdx.x * 4 + (threadIdx.x >> 6);
    int lane = threadIdx.x & 63;
    if (e >= NEDGES) return;
    int sn = src[e], dn = dst[e];
    float v = proj[(size_t)dn * DIM + lane] + proj[(size_t)sn * DIM + ADIM + lane] + b_a[lane];
    v = v > 0.0f ? v : SLOPE * v;
    v *= ratt[lane];
#pragma unroll
    for (int off = 32; off > 0; off >>= 1) v += __shfl_down(v, off);
    if (lane == 0) {
        score[e] = v;
        atomicMax(&smax_u[dn], enc_f(v));
    }
}

// ---------------- exp + segment denom ----------------
__global__ void k_expsum(const float* __restrict__ score, const int* __restrict__ dst,
                         const unsigned* __restrict__ smax_u, float* __restrict__ exv,
                         float* __restrict__ denom) {
    int e = blockIdx.x * 256 + threadIdx.x;
    if (e < NEDGES) {
        int dn = dst[e];
        float sm = dec_f(smax_u[dn]);
        float x = __expf(score[e] - sm);
        exv[e] = x;
        atomicAdd(&denom[dn], x);
    }
}

// ---------------- gates + messages via MFMA bf16 ----------------
// msgbuf != nullptr: write per-edge bf16 msg rows (LDS bounce, coalesced).
// msgbuf == nullptr: legacy fp32 atomicAdd into hN (fallback, known-correct).
__global__ __launch_bounds__(256) void k_gate_msg(
    const float* __restrict__ h, const unsigned short* __restrict__ relT,
    const int* __restrict__ sorted, const int* __restrict__ srcA, const int* __restrict__ dstA,
    const int* __restrict__ etyA, const float* __restrict__ exA, const float* __restrict__ denomA,
    float* __restrict__ hN, unsigned short* __restrict__ msgbuf) {
    __shared__ unsigned short Xs[EPB * XPITCH];  // 33792 B
    __shared__ unsigned short Ms[EPB * MPITCH];  // 17408 B
    __shared__ int eid_s[EPB];
    __shared__ int dstn_s[EPB];
    __shared__ int srcn_s[EPB];
    __shared__ float att_s[EPB];
    __shared__ int r_s;

    const int t = threadIdx.x;
    const int base = blockIdx.x * EPB;

    if (t < EPB) {
        int e = sorted[base + t];
        eid_s[t] = e;
        if (e >= 0) {
            int dn = dstA[e], sn = srcA[e];
            dstn_s[t] = dn;
            srcn_s[t] = sn;
            att_s[t] = exA[e] / denomA[dn];
        } else {
            dstn_s[t] = 0;
            srcn_s[t] = 0;
            att_s[t] = 0.0f;
        }
        if (t == 0) r_s = (e >= 0) ? etyA[e] : 0;
    }
    __syncthreads();
    if (eid_s[0] < 0) return;
    const int r = r_s;

#pragma unroll
    for (int u = 0; u < 8; u++) {
        int v = u * 256 + t;
        int i = v >> 5;
        int c = v & 31;
        int node = (c < 16) ? dstn_s[i] : srcn_s[i];
        const float4* hp = (const float4*)(h + (size_t)node * DIM + (c & 15) * 8);
        float4 a = hp[0], b = hp[1];
        union { unsigned short us[8]; short8 s8; } pk;
        pk.us[0] = f2bf(a.x); pk.us[1] = f2bf(a.y); pk.us[2] = f2bf(a.z); pk.us[3] = f2bf(a.w);
        pk.us[4] = f2bf(b.x); pk.us[5] = f2bf(b.y); pk.us[6] = f2bf(b.z); pk.us[7] = f2bf(b.w);
        *(short8*)&Xs[i * XPITCH + c * 8] = pk.s8;
    }

    const int wave = t >> 6;
    const int lane = t & 63;
    const int q = lane >> 4;
    const int l16 = lane & 15;

    short8 Bf[2][8];
#pragma unroll
    for (int nn = 0; nn < 2; nn++) {
        int o = (wave * 2 + nn) * 16 + l16;
        const unsigned short* bp = relT + ((size_t)r * DIM + o) * TWOD + q * 8;
#pragma unroll
        for (int ks = 0; ks < 8; ks++) Bf[nn][ks] = *(const short8*)(bp + ks * 32);
    }

    __syncthreads();

    floatx4 acc[4][2];
#pragma unroll
    for (int m = 0; m < 4; m++)
#pragma unroll
        for (int nn = 0; nn < 2; nn++) acc[m][nn] = (floatx4)(0.0f);

#pragma unroll
    for (int ks = 0; ks < 8; ks++) {
        short8 Af[4];
        const unsigned short* xb = &Xs[l16 * XPITCH + ks * 32 + q * 8];
#pragma unroll
        for (int m = 0; m < 4; m++) Af[m] = *(const short8*)(xb + m * 16 * XPITCH);
#pragma unroll
        for (int m = 0; m < 4; m++)
#pragma unroll
            for (int nn = 0; nn < 2; nn++)
                acc[m][nn] = __builtin_amdgcn_mfma_f32_16x16x32_bf16(Af[m], Bf[nn][ks], acc[m][nn], 0, 0, 0);
    }

    if (msgbuf) {
        // epilogue A: msg -> Ms (bf16), then coalesced stream to msgbuf[eid]
#pragma unroll
        for (int m = 0; m < 4; m++) {
            int ib = m * 16 + q * 4;
#pragma unroll
            for (int nn = 0; nn < 2; nn++) {
                int o = (wave * 2 + nn) * 16 + l16;
#pragma unroll
                for (int rg = 0; rg < 4; rg++) {
                    int i = ib + rg;
                    float g = 1.0f / (1.0f + __expf(-acc[m][nn][rg]));
                    float sh = bf2f(Xs[i * XPITCH + DIM + o]);
                    Ms[i * MPITCH + o] = f2bf(sh * att_s[i] * g);
                }
            }
        }
        __syncthreads();
#pragma unroll
        for (int u = 0; u < 4; u++) {
            int v = u * 256 + t;
            int i = v >> 4;       // row 0..63
            int c = v & 15;       // 16B chunk 0..15
            int e = eid_s[i];
            if (e < 0) continue;
            short8 val = *(const short8*)&Ms[i * MPITCH + c * 8];
            *(short8*)&msgbuf[(size_t)e * DIM + c * 8] = val;
        }
    } else {
        // epilogue B (fallback): fp32 atomics into hN
#pragma unroll
        for (int m = 0; m < 4; m++) {
            int ib = m * 16 + q * 4;
#pragma unroll
            for (int nn = 0; nn < 2; nn++) {
                int o = (wave * 2 + nn) * 16 + l16;
#pragma unroll
                for (int rg = 0; rg < 4; rg++) {
                    int i = ib + rg;
                    if (eid_s[i] < 0) continue;
                    float g = 1.0f / (1.0f + __expf(-acc[m][nn][rg]));
                    float sh = bf2f(Xs[i * XPITCH + DIM + o]);
                    float msg = sh * att_s[i] * g;
                    atomicAdd(&hN[(size_t)dstn_s[i] * DIM + o], msg);
                }
            }
        }
    }
}

// ---------------- segment-sum over dst-CSR: hN[n] = sum msg rows ----------------
__global__ __launch_bounds__(256) void k_aggr(const unsigned short* __restrict__ msgbuf,
                                              const int* __restrict__ row_ptr,
                                              const int* __restrict__ dcsr,
                                              float* __restrict__ hN) {
    int n = blockIdx.x * 2 + (threadIdx.x >> 7);
    int o = threadIdx.x & 127;
    if (n >= NNODES) return;
    int p0 = row_ptr[n], p1 = row_ptr[n + 1];
    float acc = 0.0f;
    for (int p = p0; p < p1; p++) {
        int e = dcsr[p];
        acc += bf2f(msgbuf[(size_t)e * DIM + o]);
    }
    hN[(size_t)n * DIM + o] = acc;
}

// ---------------- out = leaky(W_lin @ [h ; h_N] + b) via MFMA bf16 ----------------
__global__ __launch_bounds__(256) void k_out(const float* __restrict__ h, const float* __restrict__ hN,
                                             const unsigned short* __restrict__ Wl,
                                             const float* __restrict__ b_lin,
                                             float* __restrict__ out) {
    __shared__ unsigned short Xs[EPB * XPITCH];
    const int t = threadIdx.x;
    const int nb = blockIdx.x * 64;

#pragma unroll
    for (int u = 0; u < 8; u++) {
        int v = u * 256 + t;
        int i = v >> 5;
        int c = v & 31;
        int n = nb + i;
        if (n >= NNODES) n = NNODES - 1;
        const float* srcp = (c < 16) ? h : hN;
        const float4* hp = (const float4*)(srcp + (size_t)n * DIM + (c & 15) * 8);
        float4 a = hp[0], b = hp[1];
        union { unsigned short us[8]; short8 s8; } pk;
        pk.us[0] = f2bf(a.x); pk.us[1] = f2bf(a.y); pk.us[2] = f2bf(a.z); pk.us[3] = f2bf(a.w);
        pk.us[4] = f2bf(b.x); pk.us[5] = f2bf(b.y); pk.us[6] = f2bf(b.z); pk.us[7] = f2bf(b.w);
        *(short8*)&Xs[i * XPITCH + c * 8] = pk.s8;
    }

    const int wave = t >> 6;
    const int lane = t & 63;
    const int q = lane >> 4;
    const int l16 = lane & 15;

    short8 Bf[2][8];
#pragma unroll
    for (int nn = 0; nn < 2; nn++) {
        int o = (wave * 2 + nn) * 16 + l16;
        const unsigned short* bp = Wl + (size_t)o * TWOD + q * 8;
#pragma unroll
        for (int ks = 0; ks < 8; ks++) Bf[nn][ks] = *(const short8*)(bp + ks * 32);
    }

    __syncthreads();

    floatx4 acc[4][2];
#pragma unroll
    for (int m = 0; m < 4; m++)
#pragma unroll
        for (int nn = 0; nn < 2; nn++) acc[m][nn] = (floatx4)(0.0f);

#pragma unroll
    for (int ks = 0; ks < 8; ks++) {
        short8 Af[4];
        const unsigned short* xb = &Xs[l16 * XPITCH + ks * 32 + q * 8];
#pragma unroll
        for (int m = 0; m < 4; m++) Af[m] = *(const short8*)(xb + m * 16 * XPITCH);
#pragma unroll
        for (int m = 0; m < 4; m++)
#pragma unroll
            for (int nn = 0; nn < 2; nn++)
                acc[m][nn] = __builtin_amdgcn_mfma_f32_16x16x32_bf16(Af[m], Bf[nn][ks], acc[m][nn], 0, 0, 0);
    }

#pragma unroll
    for (int m = 0; m < 4; m++) {
        int ib = m * 16 + q * 4;
#pragma unroll
        for (int nn = 0; nn < 2; nn++) {
            int o = (wave * 2 + nn) * 16 + l16;
            float bl = b_lin[o];
#pragma unroll
            for (int rg = 0; rg < 4; rg++) {
                int n = nb + ib + rg;
                if (n < NNODES) {
                    float val = acc[m][nn][rg] + bl;
                    val = val > 0.0f ? val : SLOPE * val;
                    out[(size_t)n * DIM + o] = val;
                }
            }
        }
    }
}

// ---------------- launcher ----------------
extern "C" void kernel_launch(void* const* d_in, const int* in_sizes, int n_in,
                              void* d_out, int out_size, void* d_ws, size_t ws_size,
                              hipStream_t stream) {
    const float* h     = (const float*)d_in[0];
    const float* rel   = (const float*)d_in[1];
    const float* ratt  = (const float*)d_in[2];
    const float* W_a   = (const float*)d_in[3];
    const float* b_a   = (const float*)d_in[4];
    const float* W_lin = (const float*)d_in[5];
    const float* b_lin = (const float*)d_in[6];
    const int* src = (const int*)d_in[7];
    const int* dst = (const int*)d_in[8];
    const int* ety = (const int*)d_in[9];
    float* out = (float*)d_out;

    // base workspace layout (~58.3 MB)
    float* wsf   = (float*)d_ws;
    float* score = wsf;                                   // E
    float* exv   = score + NEDGES;                        // E
    float* denom = exv + NEDGES;                          // N
    float* proj  = denom + NNODES;                        // N*128
    float* hN    = proj + (size_t)NNODES * DIM;           // N*128
    unsigned* smax_u = (unsigned*)(hN + (size_t)NNODES * DIM);  // N
    int* sorted  = (int*)(smax_u + NNODES);               // E + 1024
    int* cnts    = sorted + (NEDGES + 1024);              // 16
    int* offs    = cnts + 16;                             // 8
    unsigned short* relT = (unsigned short*)(offs + 8);   // 8*128*256
    unsigned short* Wl   = relT + (size_t)NRELS * DIM * TWOD;  // 128*256
    unsigned short* Wa2  = Wl + (size_t)DIM * TWOD;       // 128*128
    // path-A extras
    int* histD   = (int*)(Wa2 + (size_t)DIM * DIM);       // N
    int* row_ptr = histD + NNODES;                        // N+1
    int* cursorD = row_ptr + (NNODES + 1);                // N
    int* dcsr    = cursorD + NNODES;                      // E
    unsigned short* msgbuf = (unsigned short*)(((uintptr_t)(dcsr + NEDGES) + 255) & ~(uintptr_t)255); // E*128 bf16

    size_t need = (size_t)((char*)(msgbuf + (size_t)NEDGES * DIM) - (char*)d_ws);
    bool pathA = (ws_size >= need);

    k_init<<<25000, 256, 0, stream>>>(hN, denom, smax_u, sorted, cnts,
                                      pathA ? histD : nullptr, pathA ? cursorD : nullptr);
    k_prep<<<(NRELS * TWOD * DIM + DIM * TWOD + DIM * DIM + 255) / 256, 256, 0, stream>>>(
        rel, W_lin, W_a, relT, Wl, Wa2);
    k_count<<<(NEDGES + 255) / 256, 256, 0, stream>>>(ety, cnts);
    k_prefix<<<1, 64, 0, stream>>>(cnts, offs);
    k_scatter<<<(NEDGES + 255) / 256, 256, 0, stream>>>(ety, offs, cnts + 8, sorted);
    k_nodeproj<<<(NNODES + 63) / 64, 256, 0, stream>>>(h, Wa2, proj);
    k_score<<<NEDGES / 4, 256, 0, stream>>>(proj, b_a, ratt, src, dst, score, smax_u);
    k_expsum<<<(NEDGES + 255) / 256, 256, 0, stream>>>(score, dst, smax_u, exv, denom);
    if (pathA) {
        k_histD<<<(NEDGES + 255) / 256, 256, 0, stream>>>(dst, histD);
        k_scanD<<<1, 1024, 0, stream>>>(histD, row_ptr);
        k_dscatter<<<(NEDGES + 255) / 256, 256, 0, stream>>>(dst, row_ptr, cursorD, dcsr);
        k_gate_msg<<<(NEDGES + 8 * EPB + EPB - 1) / EPB, 256, 0, stream>>>(
            h, relT, sorted, src, dst, ety, exv, denom, hN, msgbuf);
        k_aggr<<<(NNODES + 1) / 2, 256, 0, stream>>>(msgbuf, row_ptr, dcsr, hN);
    } else {
        k_gate_msg<<<(NEDGES + 8 * EPB + EPB - 1) / EPB, 256, 0, stream>>>(
            h, relT, sorted, src, dst, ety, exv, denom, hN, nullptr);
    }
    k_out<<<(NNODES + 63) / 64, 256, 0, stream>>>(h, hN, Wl, b_lin, out);
}

// Round 5
// 623.679 us; speedup vs baseline: 1.1084x; 1.1084x over previous
//
#include <hip/hip_runtime.h>
#include <cstdint>
#include <cstddef>

// ---------------- problem constants ----------------
constexpr int NNODES = 50000;
constexpr int NEDGES = 500000;
constexpr int NRELS  = 8;
constexpr int DIM    = 128;   // input/output dim
constexpr int ADIM   = 64;    // attention dim
constexpr int TWOD   = 256;   // 2*DIM
constexpr int EPB    = 64;    // edges per block in gate kernel
constexpr float SLOPE = 0.01f; // leaky_relu default slope

constexpr int XPITCH = TWOD + 8;   // LDS row pitch (bf16) for K=256 kernels
constexpr int PPITCH = DIM + 8;    // LDS row pitch for K=128 kernel
constexpr int MPITCH = DIM + 8;    // msg LDS pitch

typedef __attribute__((ext_vector_type(8))) short short8;   // 8 bf16 = 4 VGPRs
typedef __attribute__((ext_vector_type(4))) float floatx4;  // MFMA C/D frag

__device__ __forceinline__ unsigned short f2bf(float f) {
    unsigned u = __float_as_uint(f);
    unsigned r = u + 0x7FFFu + ((u >> 16) & 1u);
    return (unsigned short)(r >> 16);
}
__device__ __forceinline__ float bf2f(unsigned short b) {
    return __uint_as_float(((unsigned)b) << 16);
}
__device__ __forceinline__ unsigned enc_f(float f) {
    unsigned u = __float_as_uint(f);
    return (u & 0x80000000u) ? ~u : (u | 0x80000000u);
}
__device__ __forceinline__ float dec_f(unsigned k) {
    unsigned u = (k & 0x80000000u) ? (k & 0x7FFFFFFFu) : ~k;
    return __uint_as_float(u);
}

// ---------------- init ----------------
__global__ void k_init(float* __restrict__ hN, float* __restrict__ denom,
                       unsigned* __restrict__ smax_u, int* __restrict__ sorted,
                       int* __restrict__ cnts,
                       int* __restrict__ histD, int* __restrict__ cursorD,
                       int zero_hN) {
    int i = blockIdx.x * blockDim.x + threadIdx.x;
    int stride = gridDim.x * blockDim.x;
    if (zero_hN) for (int idx = i; idx < NNODES * DIM; idx += stride) hN[idx] = 0.0f;
    for (int idx = i; idx < NNODES; idx += stride) {
        denom[idx] = 0.0f; smax_u[idx] = 0u;
        if (histD) { histD[idx] = 0; cursorD[idx] = 0; }
    }
    for (int idx = i; idx < NEDGES + 1024; idx += stride) sorted[idx] = -1;
    if (i < 16) cnts[i] = 0;
}

// ---------------- prep: bf16 weight tables ----------------
__global__ void k_prep(const float* __restrict__ rel, const float* __restrict__ W_lin,
                       const float* __restrict__ W_a,
                       unsigned short* __restrict__ relT, unsigned short* __restrict__ Wl,
                       unsigned short* __restrict__ Wa2) {
    int idx = blockIdx.x * 256 + threadIdx.x;
    const int NREL_ELEMS = NRELS * TWOD * DIM;  // 262144
    const int WL_ELEMS = DIM * TWOD;            // 32768
    const int WA2_ELEMS = DIM * DIM;            // 16384
    if (idx < NREL_ELEMS) {
        int d = idx & 255;
        int o = (idx >> 8) & 127;
        int r = idx >> 15;
        relT[((size_t)r * DIM + o) * TWOD + d] = f2bf(rel[((size_t)r * TWOD + d) * DIM + o]);
    } else if (idx < NREL_ELEMS + WL_ELEMS) {
        int j = idx - NREL_ELEMS;
        Wl[j] = f2bf(W_lin[j]);
    } else if (idx < NREL_ELEMS + WL_ELEMS + WA2_ELEMS) {
        int j = idx - NREL_ELEMS - WL_ELEMS;
        int d = j & 127, o = j >> 7;
        float v = (o < ADIM) ? W_a[(size_t)o * TWOD + d] : W_a[(size_t)(o - ADIM) * TWOD + DIM + d];
        Wa2[j] = f2bf(v);
    }
}

// ---------------- h -> bf16 copy (halves all h gather traffic) ----------------
__global__ void k_h16(const float* __restrict__ h, unsigned short* __restrict__ h16) {
    int i = blockIdx.x * 256 + threadIdx.x;   // chunk of 8 elems
    if (i < NNODES * DIM / 8) {
        const float4* hp = (const float4*)(h + (size_t)i * 8);
        float4 a = hp[0], b = hp[1];
        union { unsigned short us[8]; short8 s8; } pk;
        pk.us[0] = f2bf(a.x); pk.us[1] = f2bf(a.y); pk.us[2] = f2bf(a.z); pk.us[3] = f2bf(a.w);
        pk.us[4] = f2bf(b.x); pk.us[5] = f2bf(b.y); pk.us[6] = f2bf(b.z); pk.us[7] = f2bf(b.w);
        *(short8*)&h16[(size_t)i * 8] = pk.s8;
    }
}

// ---------------- counting sort by etype ----------------
__global__ void k_count(const int* __restrict__ ety, int* __restrict__ cnt) {
    __shared__ int hist[NRELS];
    int t = threadIdx.x;
    if (t < NRELS) hist[t] = 0;
    __syncthreads();
    int e = blockIdx.x * 256 + t;
    if (e < NEDGES) atomicAdd(&hist[ety[e]], 1);
    __syncthreads();
    if (t < NRELS && hist[t] > 0) atomicAdd(&cnt[t], hist[t]);
}

__global__ void k_prefix(const int* __restrict__ cnt, int* __restrict__ offs) {
    if (blockIdx.x == 0 && threadIdx.x == 0) {
        int off = 0;
        for (int r = 0; r < NRELS; r++) {
            offs[r] = off;
            off += ((cnt[r] + EPB - 1) / EPB) * EPB;
        }
    }
}

__global__ void k_scatter(const int* __restrict__ ety, const int* __restrict__ offs,
                          int* __restrict__ cursor, int* __restrict__ sorted) {
    __shared__ int hist[NRELS];
    __shared__ int basew[NRELS];
    int t = threadIdx.x;
    if (t < NRELS) hist[t] = 0;
    __syncthreads();
    int e = blockIdx.x * 256 + t;
    int r = -1, rank = 0;
    if (e < NEDGES) { r = ety[e]; rank = atomicAdd(&hist[r], 1); }
    __syncthreads();
    if (t < NRELS && hist[t] > 0) basew[t] = atomicAdd(&cursor[t], hist[t]);
    __syncthreads();
    if (e < NEDGES) sorted[offs[r] + basew[r] + rank] = e;
}

// ---------------- dst-CSR build ----------------
__global__ void k_histD(const int* __restrict__ dst, int* __restrict__ histD) {
    int e = blockIdx.x * 256 + threadIdx.x;
    if (e < NEDGES) atomicAdd(&histD[dst[e]], 1);
}

__global__ __launch_bounds__(1024) void k_scanD(const int* __restrict__ histD,
                                                int* __restrict__ row_ptr) {
    __shared__ int ls[1024];
    const int t = threadIdx.x;
    const int CH = (NNODES + 1023) / 1024;  // 49
    const int base = t * CH;
    int s = 0;
    for (int j = 0; j < CH; j++) { int i = base + j; if (i < NNODES) s += histD[i]; }
    ls[t] = s;
    __syncthreads();
    for (int off = 1; off < 1024; off <<= 1) {
        int v = (t >= off) ? ls[t - off] : 0;
        __syncthreads();
        ls[t] += v;
        __syncthreads();
    }
    int run = (t == 0) ? 0 : ls[t - 1];
    for (int j = 0; j < CH; j++) {
        int i = base + j;
        if (i < NNODES) { row_ptr[i] = run; run += histD[i]; }
    }
    if (t == 1023) row_ptr[NNODES] = ls[1023];
}

// pos[e] = position of edge e in the dst-sorted run (rank order arbitrary; sums are order-free)
__global__ void k_dscatter(const int* __restrict__ dst, const int* __restrict__ row_ptr,
                           int* __restrict__ cursorD, int* __restrict__ pos) {
    int e = blockIdx.x * 256 + threadIdx.x;
    if (e < NEDGES) {
        int dn = dst[e];
        pos[e] = row_ptr[dn] + atomicAdd(&cursorD[dn], 1);
    }
}

// ---------------- node attention projections via MFMA -> bf16 proj ----------------
__global__ __launch_bounds__(256) void k_nodeproj(const unsigned short* __restrict__ h16,
                                                  const unsigned short* __restrict__ Wa2,
                                                  unsigned short* __restrict__ proj16) {
    __shared__ unsigned short Xs[EPB * PPITCH];
    const int t = threadIdx.x;
    const int nb = blockIdx.x * 64;

    // stage 64 rows x 128 bf16; 1024 chunks of 8 / 256 threads = 4 each
#pragma unroll
    for (int u = 0; u < 4; u++) {
        int v = u * 256 + t;
        int i = v >> 4;
        int c = v & 15;
        int n = nb + i;
        if (n >= NNODES) n = NNODES - 1;
        *(short8*)&Xs[i * PPITCH + c * 8] = *(const short8*)&h16[(size_t)n * DIM + c * 8];
    }

    const int wave = t >> 6;
    const int lane = t & 63;
    const int q = lane >> 4;
    const int l16 = lane & 15;

    short8 Bf[2][4];
#pragma unroll
    for (int nn = 0; nn < 2; nn++) {
        int o = (wave * 2 + nn) * 16 + l16;
        const unsigned short* bp = Wa2 + (size_t)o * DIM + q * 8;
#pragma unroll
        for (int ks = 0; ks < 4; ks++) Bf[nn][ks] = *(const short8*)(bp + ks * 32);
    }

    __syncthreads();

    floatx4 acc[4][2];
#pragma unroll
    for (int m = 0; m < 4; m++)
#pragma unroll
        for (int nn = 0; nn < 2; nn++) acc[m][nn] = (floatx4)(0.0f);

#pragma unroll
    for (int ks = 0; ks < 4; ks++) {
        short8 Af[4];
        const unsigned short* xb = &Xs[l16 * PPITCH + ks * 32 + q * 8];
#pragma unroll
        for (int m = 0; m < 4; m++) Af[m] = *(const short8*)(xb + m * 16 * PPITCH);
#pragma unroll
        for (int m = 0; m < 4; m++)
#pragma unroll
            for (int nn = 0; nn < 2; nn++)
                acc[m][nn] = __builtin_amdgcn_mfma_f32_16x16x32_bf16(Af[m], Bf[nn][ks], acc[m][nn], 0, 0, 0);
    }

#pragma unroll
    for (int m = 0; m < 4; m++) {
        int ib = m * 16 + q * 4;
#pragma unroll
        for (int nn = 0; nn < 2; nn++) {
            int o = (wave * 2 + nn) * 16 + l16;
#pragma unroll
            for (int rg = 0; rg < 4; rg++) {
                int n = nb + ib + rg;
                if (n < NNODES) proj16[(size_t)n * DIM + o] = f2bf(acc[m][nn][rg]);
            }
        }
    }
}

// ---------------- per-edge score + segment max (wave per edge) ----------------
__global__ __launch_bounds__(256) void k_score(const unsigned short* __restrict__ proj16,
                                               const float* __restrict__ b_a, const float* __restrict__ ratt,
                                               const int* __restrict__ src, const int* __restrict__ dst,
                                               float* __restrict__ score, unsigned* __restrict__ smax_u) {
    int e = blockIdx.x * 4 + (threadIdx.x >> 6);
    int lane = threadIdx.x & 63;
    if (e >= NEDGES) return;
    int sn = src[e], dn = dst[e];
    float v = bf2f(proj16[(size_t)dn * DIM + lane]) + bf2f(proj16[(size_t)sn * DIM + ADIM + lane]) + b_a[lane];
    v = v > 0.0f ? v : SLOPE * v;
    v *= ratt[lane];
#pragma unroll
    for (int off = 32; off > 0; off >>= 1) v += __shfl_down(v, off);
    if (lane == 0) {
        score[e] = v;
        atomicMax(&smax_u[dn], enc_f(v));
    }
}

// ---------------- exp + segment denom ----------------
__global__ void k_expsum(const float* __restrict__ score, const int* __restrict__ dst,
                         const unsigned* __restrict__ smax_u, float* __restrict__ exv,
                         float* __restrict__ denom) {
    int e = blockIdx.x * 256 + threadIdx.x;
    if (e < NEDGES) {
        int dn = dst[e];
        float sm = dec_f(smax_u[dn]);
        float x = __expf(score[e] - sm);
        exv[e] = x;
        atomicAdd(&denom[dn], x);
    }
}

// ---------------- gates + messages via MFMA bf16 ----------------
// Path A (msgbuf!=null): write bf16 msg rows at dst-CSR position -> k_aggr streams sequentially.
// Path B (msgbuf==null): fp32 atomicAdd into hN (fallback).
__global__ __launch_bounds__(256) void k_gate_msg(
    const unsigned short* __restrict__ h16, const unsigned short* __restrict__ relT,
    const int* __restrict__ sorted, const int* __restrict__ srcA, const int* __restrict__ dstA,
    const int* __restrict__ etyA, const float* __restrict__ exA, const float* __restrict__ denomA,
    const int* __restrict__ pos,
    float* __restrict__ hN, unsigned short* __restrict__ msgbuf) {
    __shared__ unsigned short Xs[EPB * XPITCH];  // 33792 B
    __shared__ unsigned short Ms[EPB * MPITCH];  // 17408 B
    __shared__ int eid_s[EPB];
    __shared__ int dstn_s[EPB];
    __shared__ int srcn_s[EPB];
    __shared__ int pos_s[EPB];
    __shared__ float att_s[EPB];
    __shared__ int r_s;

    const int t = threadIdx.x;
    const int base = blockIdx.x * EPB;

    if (t < EPB) {
        int e = sorted[base + t];
        eid_s[t] = e;
        if (e >= 0) {
            int dn = dstA[e], sn = srcA[e];
            dstn_s[t] = dn;
            srcn_s[t] = sn;
            att_s[t] = exA[e] / denomA[dn];
            pos_s[t] = pos ? pos[e] : 0;
        } else {
            dstn_s[t] = 0;
            srcn_s[t] = 0;
            att_s[t] = 0.0f;
            pos_s[t] = 0;
        }
        if (t == 0) r_s = (e >= 0) ? etyA[e] : 0;
    }
    __syncthreads();
    if (eid_s[0] < 0) return;
    const int r = r_s;

    // stage X from bf16 h: 64 rows x 32 chunks (16B), 8 per thread
#pragma unroll
    for (int u = 0; u < 8; u++) {
        int v = u * 256 + t;
        int i = v >> 5;
        int c = v & 31;
        int node = (c < 16) ? dstn_s[i] : srcn_s[i];
        *(short8*)&Xs[i * XPITCH + c * 8] = *(const short8*)&h16[(size_t)node * DIM + (c & 15) * 8];
    }

    const int wave = t >> 6;
    const int lane = t & 63;
    const int q = lane >> 4;
    const int l16 = lane & 15;

    short8 Bf[2][8];
#pragma unroll
    for (int nn = 0; nn < 2; nn++) {
        int o = (wave * 2 + nn) * 16 + l16;
        const unsigned short* bp = relT + ((size_t)r * DIM + o) * TWOD + q * 8;
#pragma unroll
        for (int ks = 0; ks < 8; ks++) Bf[nn][ks] = *(const short8*)(bp + ks * 32);
    }

    __syncthreads();

    floatx4 acc[4][2];
#pragma unroll
    for (int m = 0; m < 4; m++)
#pragma unroll
        for (int nn = 0; nn < 2; nn++) acc[m][nn] = (floatx4)(0.0f);

#pragma unroll
    for (int ks = 0; ks < 8; ks++) {
        short8 Af[4];
        const unsigned short* xb = &Xs[l16 * XPITCH + ks * 32 + q * 8];
#pragma unroll
        for (int m = 0; m < 4; m++) Af[m] = *(const short8*)(xb + m * 16 * XPITCH);
#pragma unroll
        for (int m = 0; m < 4; m++)
#pragma unroll
            for (int nn = 0; nn < 2; nn++)
                acc[m][nn] = __builtin_amdgcn_mfma_f32_16x16x32_bf16(Af[m], Bf[nn][ks], acc[m][nn], 0, 0, 0);
    }

    if (msgbuf) {
#pragma unroll
        for (int m = 0; m < 4; m++) {
            int ib = m * 16 + q * 4;
#pragma unroll
            for (int nn = 0; nn < 2; nn++) {
                int o = (wave * 2 + nn) * 16 + l16;
#pragma unroll
                for (int rg = 0; rg < 4; rg++) {
                    int i = ib + rg;
                    float g = 1.0f / (1.0f + __expf(-acc[m][nn][rg]));
                    float sh = bf2f(Xs[i * XPITCH + DIM + o]);
                    Ms[i * MPITCH + o] = f2bf(sh * att_s[i] * g);
                }
            }
        }
        __syncthreads();
#pragma unroll
        for (int u = 0; u < 4; u++) {
            int v = u * 256 + t;
            int i = v >> 4;       // row
            int c = v & 15;       // 16B chunk
            if (eid_s[i] < 0) continue;
            short8 val = *(const short8*)&Ms[i * MPITCH + c * 8];
            *(short8*)&msgbuf[(size_t)pos_s[i] * DIM + c * 8] = val;
        }
    } else {
#pragma unroll
        for (int m = 0; m < 4; m++) {
            int ib = m * 16 + q * 4;
#pragma unroll
            for (int nn = 0; nn < 2; nn++) {
                int o = (wave * 2 + nn) * 16 + l16;
#pragma unroll
                for (int rg = 0; rg < 4; rg++) {
                    int i = ib + rg;
                    if (eid_s[i] < 0) continue;
                    float g = 1.0f / (1.0f + __expf(-acc[m][nn][rg]));
                    float sh = bf2f(Xs[i * XPITCH + DIM + o]);
                    float msg = sh * att_s[i] * g;
                    atomicAdd(&hN[(size_t)dstn_s[i] * DIM + o], msg);
                }
            }
        }
    }
}

// ---------------- segment-sum: msg rows are dst-contiguous -> sequential stream ----------------
__global__ __launch_bounds__(256) void k_aggr(const unsigned short* __restrict__ msgbuf,
                                              const int* __restrict__ row_ptr,
                                              float* __restrict__ hN) {
    int n = blockIdx.x * 4 + (threadIdx.x >> 6);
    int lane = threadIdx.x & 63;
    if (n >= NNODES) return;
    int p0 = row_ptr[n], p1 = row_ptr[n + 1];
    float a0 = 0.0f, a1 = 0.0f;
    for (int p = p0; p < p1; p++) {
        unsigned v = *(const unsigned*)&msgbuf[(size_t)p * DIM + lane * 2];
        a0 += bf2f((unsigned short)(v & 0xFFFFu));
        a1 += bf2f((unsigned short)(v >> 16));
    }
    float2 rv; rv.x = a0; rv.y = a1;
    *(float2*)&hN[(size_t)n * DIM + lane * 2] = rv;
}

// ---------------- out = leaky(W_lin @ [h ; h_N] + b) via MFMA bf16 ----------------
__global__ __launch_bounds__(256) void k_out(const unsigned short* __restrict__ h16,
                                             const float* __restrict__ hN,
                                             const unsigned short* __restrict__ Wl,
                                             const float* __restrict__ b_lin,
                                             float* __restrict__ out) {
    __shared__ unsigned short Xs[EPB * XPITCH];
    const int t = threadIdx.x;
    const int nb = blockIdx.x * 64;

#pragma unroll
    for (int u = 0; u < 8; u++) {
        int v = u * 256 + t;
        int i = v >> 5;
        int c = v & 31;
        int n = nb + i;
        if (n >= NNODES) n = NNODES - 1;
        if (c < 16) {
            *(short8*)&Xs[i * XPITCH + c * 8] = *(const short8*)&h16[(size_t)n * DIM + c * 8];
        } else {
            const float4* hp = (const float4*)(hN + (size_t)n * DIM + (c & 15) * 8);
            float4 a = hp[0], b = hp[1];
            union { unsigned short us[8]; short8 s8; } pk;
            pk.us[0] = f2bf(a.x); pk.us[1] = f2bf(a.y); pk.us[2] = f2bf(a.z); pk.us[3] = f2bf(a.w);
            pk.us[4] = f2bf(b.x); pk.us[5] = f2bf(b.y); pk.us[6] = f2bf(b.z); pk.us[7] = f2bf(b.w);
            *(short8*)&Xs[i * XPITCH + c * 8] = pk.s8;
        }
    }

    const int wave = t >> 6;
    const int lane = t & 63;
    const int q = lane >> 4;
    const int l16 = lane & 15;

    short8 Bf[2][8];
#pragma unroll
    for (int nn = 0; nn < 2; nn++) {
        int o = (wave * 2 + nn) * 16 + l16;
        const unsigned short* bp = Wl + (size_t)o * TWOD + q * 8;
#pragma unroll
        for (int ks = 0; ks < 8; ks++) Bf[nn][ks] = *(const short8*)(bp + ks * 32);
    }

    __syncthreads();

    floatx4 acc[4][2];
#pragma unroll
    for (int m = 0; m < 4; m++)
#pragma unroll
        for (int nn = 0; nn < 2; nn++) acc[m][nn] = (floatx4)(0.0f);

#pragma unroll
    for (int ks = 0; ks < 8; ks++) {
        short8 Af[4];
        const unsigned short* xb = &Xs[l16 * XPITCH + ks * 32 + q * 8];
#pragma unroll
        for (int m = 0; m < 4; m++) Af[m] = *(const short8*)(xb + m * 16 * XPITCH);
#pragma unroll
        for (int m = 0; m < 4; m++)
#pragma unroll
            for (int nn = 0; nn < 2; nn++)
                acc[m][nn] = __builtin_amdgcn_mfma_f32_16x16x32_bf16(Af[m], Bf[nn][ks], acc[m][nn], 0, 0, 0);
    }

#pragma unroll
    for (int m = 0; m < 4; m++) {
        int ib = m * 16 + q * 4;
#pragma unroll
        for (int nn = 0; nn < 2; nn++) {
            int o = (wave * 2 + nn) * 16 + l16;
            float bl = b_lin[o];
#pragma unroll
            for (int rg = 0; rg < 4; rg++) {
                int n = nb + ib + rg;
                if (n < NNODES) {
                    float val = acc[m][nn][rg] + bl;
                    val = val > 0.0f ? val : SLOPE * val;
                    out[(size_t)n * DIM + o] = val;
                }
            }
        }
    }
}

// ---------------- launcher ----------------
extern "C" void kernel_launch(void* const* d_in, const int* in_sizes, int n_in,
                              void* d_out, int out_size, void* d_ws, size_t ws_size,
                              hipStream_t stream) {
    const float* h     = (const float*)d_in[0];
    const float* rel   = (const float*)d_in[1];
    const float* ratt  = (const float*)d_in[2];
    const float* W_a   = (const float*)d_in[3];
    const float* b_a   = (const float*)d_in[4];
    const float* W_lin = (const float*)d_in[5];
    const float* b_lin = (const float*)d_in[6];
    const int* src = (const int*)d_in[7];
    const int* dst = (const int*)d_in[8];
    const int* ety = (const int*)d_in[9];
    float* out = (float*)d_out;

    // workspace layout
    float* wsf   = (float*)d_ws;
    float* score = wsf;                                   // E
    float* exv   = score + NEDGES;                        // E
    float* denom = exv + NEDGES;                          // N
    float* hN    = denom + NNODES;                        // N*128
    unsigned* smax_u = (unsigned*)(hN + (size_t)NNODES * DIM);  // N
    int* sorted  = (int*)(smax_u + NNODES);               // E + 1024
    int* cnts    = sorted + (NEDGES + 1024);              // 16
    int* offs    = cnts + 16;                             // 8
    unsigned short* relT = (unsigned short*)(offs + 8);   // 8*128*256
    unsigned short* Wl   = relT + (size_t)NRELS * DIM * TWOD;  // 128*256
    unsigned short* Wa2  = Wl + (size_t)DIM * TWOD;       // 128*128
    unsigned short* proj16 = Wa2 + (size_t)DIM * DIM;     // N*128 bf16
    unsigned short* h16  = proj16 + (size_t)NNODES * DIM; // N*128 bf16
    // path-A extras
    int* histD   = (int*)(h16 + (size_t)NNODES * DIM);    // N
    int* row_ptr = histD + NNODES;                        // N+1
    int* cursorD = row_ptr + (NNODES + 1);                // N
    int* pos     = cursorD + NNODES;                      // E
    unsigned short* msgbuf = (unsigned short*)(((uintptr_t)(pos + NEDGES) + 255) & ~(uintptr_t)255); // E*128 bf16

    size_t need = (size_t)((char*)(msgbuf + (size_t)NEDGES * DIM) - (char*)d_ws);
    bool pathA = (ws_size >= need);

    k_init<<<25000, 256, 0, stream>>>(hN, denom, smax_u, sorted, cnts,
                                      pathA ? histD : nullptr, pathA ? cursorD : nullptr,
                                      pathA ? 0 : 1);
    k_prep<<<(NRELS * TWOD * DIM + DIM * TWOD + DIM * DIM + 255) / 256, 256, 0, stream>>>(
        rel, W_lin, W_a, relT, Wl, Wa2);
    k_h16<<<(NNODES * DIM / 8 + 255) / 256, 256, 0, stream>>>(h, h16);
    k_count<<<(NEDGES + 255) / 256, 256, 0, stream>>>(ety, cnts);
    k_prefix<<<1, 64, 0, stream>>>(cnts, offs);
    k_scatter<<<(NEDGES + 255) / 256, 256, 0, stream>>>(ety, offs, cnts + 8, sorted);
    k_nodeproj<<<(NNODES + 63) / 64, 256, 0, stream>>>(h16, Wa2, proj16);
    k_score<<<NEDGES / 4, 256, 0, stream>>>(proj16, b_a, ratt, src, dst, score, smax_u);
    k_expsum<<<(NEDGES + 255) / 256, 256, 0, stream>>>(score, dst, smax_u, exv, denom);
    if (pathA) {
        k_histD<<<(NEDGES + 255) / 256, 256, 0, stream>>>(dst, histD);
        k_scanD<<<1, 1024, 0, stream>>>(histD, row_ptr);
        k_dscatter<<<(NEDGES + 255) / 256, 256, 0, stream>>>(dst, row_ptr, cursorD, pos);
        k_gate_msg<<<(NEDGES + 8 * EPB + EPB - 1) / EPB, 256, 0, stream>>>(
            h16, relT, sorted, src, dst, ety, exv, denom, pos, hN, msgbuf);
        k_aggr<<<(NNODES + 3) / 4, 256, 0, stream>>>(msgbuf, row_ptr, hN);
    } else {
        k_gate_msg<<<(NEDGES + 8 * EPB + EPB - 1) / EPB, 256, 0, stream>>>(
            h16, relT, sorted, src, dst, ety, exv, denom, nullptr, hN, nullptr);
    }
    k_out<<<(NNODES + 63) / 64, 256, 0, stream>>>(h16, hN, Wl, b_lin, out);
}

// Round 6
// 585.040 us; speedup vs baseline: 1.1816x; 1.0660x over previous
//
#include <hip/hip_runtime.h>
#include <cstdint>
#include <cstddef>

// ---------------- problem constants ----------------
constexpr int NNODES = 50000;
constexpr int NEDGES = 500000;
constexpr int NRELS  = 8;
constexpr int DIM    = 128;   // input/output dim
constexpr int ADIM   = 64;    // attention dim
constexpr int TWOD   = 256;   // 2*DIM
constexpr int EPB    = 64;    // edges per block in gate kernel
constexpr float SLOPE = 0.01f;

constexpr int XPITCH = TWOD + 8;   // LDS row pitch (bf16) K=256 kernels
constexpr int PPITCH = DIM + 8;    // LDS row pitch K=128 kernel
constexpr int MPITCH = DIM + 8;    // msg LDS pitch

constexpr int SPAD = NEDGES + 1024;  // padded sorted-space array length

typedef __attribute__((ext_vector_type(8))) short short8;
typedef __attribute__((ext_vector_type(4))) float floatx4;

__device__ __forceinline__ unsigned short f2bf(float f) {
    unsigned u = __float_as_uint(f);
    unsigned r = u + 0x7FFFu + ((u >> 16) & 1u);
    return (unsigned short)(r >> 16);
}
__device__ __forceinline__ float bf2f(unsigned short b) {
    return __uint_as_float(((unsigned)b) << 16);
}

// ---------------- init: srcS = -1, counters = 0 ----------------
__global__ void k_init(int* __restrict__ srcS, int* __restrict__ histD,
                       int* __restrict__ cursorD, int* __restrict__ cnts) {
    int i = blockIdx.x * blockDim.x + threadIdx.x;
    int stride = gridDim.x * blockDim.x;
    for (int idx = i; idx < SPAD; idx += stride) srcS[idx] = -1;
    for (int idx = i; idx < NNODES; idx += stride) { histD[idx] = 0; cursorD[idx] = 0; }
    if (i < 16) cnts[i] = 0;
}

// ---------------- prep: bf16 weight tables ----------------
__global__ void k_prep(const float* __restrict__ rel, const float* __restrict__ W_lin,
                       const float* __restrict__ W_a,
                       unsigned short* __restrict__ relT, unsigned short* __restrict__ Wl,
                       unsigned short* __restrict__ Wa2) {
    int idx = blockIdx.x * 256 + threadIdx.x;
    const int NREL_ELEMS = NRELS * TWOD * DIM;  // 262144
    const int WL_ELEMS = DIM * TWOD;            // 32768
    const int WA2_ELEMS = DIM * DIM;            // 16384
    if (idx < NREL_ELEMS) {
        int d = idx & 255;
        int o = (idx >> 8) & 127;
        int r = idx >> 15;
        relT[((size_t)r * DIM + o) * TWOD + d] = f2bf(rel[((size_t)r * TWOD + d) * DIM + o]);
    } else if (idx < NREL_ELEMS + WL_ELEMS) {
        int j = idx - NREL_ELEMS;
        Wl[j] = f2bf(W_lin[j]);
    } else if (idx < NREL_ELEMS + WL_ELEMS + WA2_ELEMS) {
        int j = idx - NREL_ELEMS - WL_ELEMS;
        int d = j & 127, o = j >> 7;
        float v = (o < ADIM) ? W_a[(size_t)o * TWOD + d] : W_a[(size_t)(o - ADIM) * TWOD + DIM + d];
        Wa2[j] = f2bf(v);
    }
}

// ---------------- h -> bf16 ----------------
__global__ void k_h16(const float* __restrict__ h, unsigned short* __restrict__ h16) {
    int i = blockIdx.x * 256 + threadIdx.x;
    if (i < NNODES * DIM / 8) {
        const float4* hp = (const float4*)(h + (size_t)i * 8);
        float4 a = hp[0], b = hp[1];
        union { unsigned short us[8]; short8 s8; } pk;
        pk.us[0] = f2bf(a.x); pk.us[1] = f2bf(a.y); pk.us[2] = f2bf(a.z); pk.us[3] = f2bf(a.w);
        pk.us[4] = f2bf(b.x); pk.us[5] = f2bf(b.y); pk.us[6] = f2bf(b.z); pk.us[7] = f2bf(b.w);
        *(short8*)&h16[(size_t)i * 8] = pk.s8;
    }
}

// ---------------- fused histogram: etype counts + dst histogram ----------------
__global__ void k_hist2(const int* __restrict__ ety, const int* __restrict__ dst,
                        int* __restrict__ cnt, int* __restrict__ histD) {
    __shared__ int hist[NRELS];
    int t = threadIdx.x;
    if (t < NRELS) hist[t] = 0;
    __syncthreads();
    int e = blockIdx.x * 256 + t;
    if (e < NEDGES) {
        atomicAdd(&hist[ety[e]], 1);
        atomicAdd(&histD[dst[e]], 1);
    }
    __syncthreads();
    if (t < NRELS && hist[t] > 0) atomicAdd(&cnt[t], hist[t]);
}

// ---------------- fused scan: dst row_ptr + etype bucket offsets ----------------
__global__ __launch_bounds__(1024) void k_scan(const int* __restrict__ histD,
                                               int* __restrict__ row_ptr,
                                               const int* __restrict__ cnt,
                                               int* __restrict__ offs) {
    __shared__ int ls[1024];
    const int t = threadIdx.x;
    const int CH = (NNODES + 1023) / 1024;  // 49
    const int base = t * CH;
    int s = 0;
    for (int j = 0; j < CH; j++) { int i = base + j; if (i < NNODES) s += histD[i]; }
    ls[t] = s;
    __syncthreads();
    for (int off = 1; off < 1024; off <<= 1) {
        int v = (t >= off) ? ls[t - off] : 0;
        __syncthreads();
        ls[t] += v;
        __syncthreads();
    }
    int run = (t == 0) ? 0 : ls[t - 1];
    for (int j = 0; j < CH; j++) {
        int i = base + j;
        if (i < NNODES) { row_ptr[i] = run; run += histD[i]; }
    }
    if (t == 1023) row_ptr[NNODES] = ls[1023];
    if (t == 0) {
        int off = 0;
        for (int r = 0; r < NRELS; r++) {
            offs[r] = off;
            off += ((cnt[r] + EPB - 1) / EPB) * EPB;
        }
    }
}

// ---------------- fused scatter: etype-sorted metadata + dst-CSR position ----------------
// srcS[s], dstS[s], posS[s] indexed by etype-sorted slot s -> gate reads coalesced.
__global__ void k_scatter2(const int* __restrict__ ety, const int* __restrict__ src,
                           const int* __restrict__ dst,
                           const int* __restrict__ offs, const int* __restrict__ row_ptr,
                           int* __restrict__ cursorE, int* __restrict__ cursorD,
                           int* __restrict__ srcS, int* __restrict__ dstS,
                           int* __restrict__ posS) {
    __shared__ int hist[NRELS];
    __shared__ int basew[NRELS];
    int t = threadIdx.x;
    if (t < NRELS) hist[t] = 0;
    __syncthreads();
    int e = blockIdx.x * 256 + t;
    int r = -1, rank = 0, sn = 0, dn = 0;
    if (e < NEDGES) {
        r = ety[e]; sn = src[e]; dn = dst[e];
        rank = atomicAdd(&hist[r], 1);
    }
    __syncthreads();
    if (t < NRELS && hist[t] > 0) basew[t] = atomicAdd(&cursorE[t], hist[t]);
    __syncthreads();
    if (e < NEDGES) {
        int s = offs[r] + basew[r] + rank;
        int pos = row_ptr[dn] + atomicAdd(&cursorD[dn], 1);
        srcS[s] = sn;
        dstS[s] = dn;
        posS[s] = pos;
    }
}

// ---------------- node attention projections via MFMA -> bf16 ----------------
__global__ __launch_bounds__(256) void k_nodeproj(const unsigned short* __restrict__ h16,
                                                  const unsigned short* __restrict__ Wa2,
                                                  unsigned short* __restrict__ proj16) {
    __shared__ unsigned short Xs[EPB * PPITCH];
    const int t = threadIdx.x;
    const int nb = blockIdx.x * 64;

#pragma unroll
    for (int u = 0; u < 4; u++) {
        int v = u * 256 + t;
        int i = v >> 4;
        int c = v & 15;
        int n = nb + i;
        if (n >= NNODES) n = NNODES - 1;
        *(short8*)&Xs[i * PPITCH + c * 8] = *(const short8*)&h16[(size_t)n * DIM + c * 8];
    }

    const int wave = t >> 6;
    const int lane = t & 63;
    const int q = lane >> 4;
    const int l16 = lane & 15;

    short8 Bf[2][4];
#pragma unroll
    for (int nn = 0; nn < 2; nn++) {
        int o = (wave * 2 + nn) * 16 + l16;
        const unsigned short* bp = Wa2 + (size_t)o * DIM + q * 8;
#pragma unroll
        for (int ks = 0; ks < 4; ks++) Bf[nn][ks] = *(const short8*)(bp + ks * 32);
    }

    __syncthreads();

    floatx4 acc[4][2];
#pragma unroll
    for (int m = 0; m < 4; m++)
#pragma unroll
        for (int nn = 0; nn < 2; nn++) acc[m][nn] = (floatx4)(0.0f);

#pragma unroll
    for (int ks = 0; ks < 4; ks++) {
        short8 Af[4];
        const unsigned short* xb = &Xs[l16 * PPITCH + ks * 32 + q * 8];
#pragma unroll
        for (int m = 0; m < 4; m++) Af[m] = *(const short8*)(xb + m * 16 * PPITCH);
#pragma unroll
        for (int m = 0; m < 4; m++)
#pragma unroll
            for (int nn = 0; nn < 2; nn++)
                acc[m][nn] = __builtin_amdgcn_mfma_f32_16x16x32_bf16(Af[m], Bf[nn][ks], acc[m][nn], 0, 0, 0);
    }

#pragma unroll
    for (int m = 0; m < 4; m++) {
        int ib = m * 16 + q * 4;
#pragma unroll
        for (int nn = 0; nn < 2; nn++) {
            int o = (wave * 2 + nn) * 16 + l16;
#pragma unroll
            for (int rg = 0; rg < 4; rg++) {
                int n = nb + ib + rg;
                if (n < NNODES) proj16[(size_t)n * DIM + o] = f2bf(acc[m][nn][rg]);
            }
        }
    }
}

// ---------------- score (s-indexed, coalesced metadata) -> scoreP[posS[s]] ----------------
__global__ __launch_bounds__(256) void k_score(const unsigned short* __restrict__ proj16,
                                               const float* __restrict__ b_a, const float* __restrict__ ratt,
                                               const int* __restrict__ srcS, const int* __restrict__ dstS,
                                               const int* __restrict__ posS,
                                               float* __restrict__ scoreP) {
    int s = blockIdx.x * 4 + (threadIdx.x >> 6);
    int lane = threadIdx.x & 63;
    if (s >= SPAD) return;
    int sn = srcS[s];
    if (sn < 0) return;
    int dn = dstS[s];
    float v = bf2f(proj16[(size_t)dn * DIM + lane]) + bf2f(proj16[(size_t)sn * DIM + ADIM + lane]) + b_a[lane];
    v = v > 0.0f ? v : SLOPE * v;
    v *= ratt[lane];
#pragma unroll
    for (int off = 32; off > 0; off >>= 1) v += __shfl_down(v, off);
    if (lane == 0) scoreP[posS[s]] = v;
}

// ---------------- segment softmax over CSR runs (atomic-free, in-place) ----------------
__global__ __launch_bounds__(256) void k_segsoft(float* __restrict__ scoreP,
                                                 const int* __restrict__ row_ptr) {
    int n = blockIdx.x * 4 + (threadIdx.x >> 6);
    int lane = threadIdx.x & 63;
    if (n >= NNODES) return;
    int p0 = row_ptr[n], p1 = row_ptr[n + 1];
    if (p0 >= p1) return;
    float m = -3.0e38f;
    for (int p = p0 + lane; p < p1; p += 64) m = fmaxf(m, scoreP[p]);
#pragma unroll
    for (int off = 32; off > 0; off >>= 1) m = fmaxf(m, __shfl_xor(m, off));
    float sum = 0.0f;
    for (int p = p0 + lane; p < p1; p += 64) {
        float x = __expf(scoreP[p] - m);
        scoreP[p] = x;
        sum += x;
    }
#pragma unroll
    for (int off = 32; off > 0; off >>= 1) sum += __shfl_xor(sum, off);
    float inv = 1.0f / sum;
    for (int p = p0 + lane; p < p1; p += 64) scoreP[p] *= inv;
}

// ---------------- gates + messages via MFMA (coalesced metadata) ----------------
__global__ __launch_bounds__(256) void k_gate_msg(
    const unsigned short* __restrict__ h16, const unsigned short* __restrict__ relT,
    const int* __restrict__ srcS, const int* __restrict__ dstS, const int* __restrict__ posS,
    const float* __restrict__ attP, const int* __restrict__ offs,
    unsigned short* __restrict__ msgbuf) {
    __shared__ unsigned short Xs[EPB * XPITCH];  // 33792 B
    __shared__ unsigned short Ms[EPB * MPITCH];  // 17408 B
    __shared__ int srcn_s[EPB];
    __shared__ int dstn_s[EPB];
    __shared__ int pos_s[EPB];
    __shared__ float att_s[EPB];
    __shared__ int val_s[EPB];

    const int t = threadIdx.x;
    const int base = blockIdx.x * EPB;

    if (t < EPB) {
        int s = base + t;
        int sv = srcS[s];
        int valid = sv >= 0;
        val_s[t] = valid;
        srcn_s[t] = valid ? sv : 0;
        dstn_s[t] = valid ? dstS[s] : 0;
        int pv = valid ? posS[s] : 0;
        pos_s[t] = pv;
        att_s[t] = valid ? attP[pv] : 0.0f;
    }
    __syncthreads();
    if (!val_s[0]) return;  // padded block (bucket-tail padding is block-aligned)

    // relation id: largest r with offs[r] <= base (wave-uniform)
    int r = 0;
#pragma unroll
    for (int i = 1; i < NRELS; i++) if (base >= offs[i]) r = i;

    // stage X: 64 rows x 256 bf16
#pragma unroll
    for (int u = 0; u < 8; u++) {
        int v = u * 256 + t;
        int i = v >> 5;
        int c = v & 31;
        int node = (c < 16) ? dstn_s[i] : srcn_s[i];
        *(short8*)&Xs[i * XPITCH + c * 8] = *(const short8*)&h16[(size_t)node * DIM + (c & 15) * 8];
    }

    const int wave = t >> 6;
    const int lane = t & 63;
    const int q = lane >> 4;
    const int l16 = lane & 15;

    short8 Bf[2][8];
#pragma unroll
    for (int nn = 0; nn < 2; nn++) {
        int o = (wave * 2 + nn) * 16 + l16;
        const unsigned short* bp = relT + ((size_t)r * DIM + o) * TWOD + q * 8;
#pragma unroll
        for (int ks = 0; ks < 8; ks++) Bf[nn][ks] = *(const short8*)(bp + ks * 32);
    }

    __syncthreads();

    floatx4 acc[4][2];
#pragma unroll
    for (int m = 0; m < 4; m++)
#pragma unroll
        for (int nn = 0; nn < 2; nn++) acc[m][nn] = (floatx4)(0.0f);

#pragma unroll
    for (int ks = 0; ks < 8; ks++) {
        short8 Af[4];
        const unsigned short* xb = &Xs[l16 * XPITCH + ks * 32 + q * 8];
#pragma unroll
        for (int m = 0; m < 4; m++) Af[m] = *(const short8*)(xb + m * 16 * XPITCH);
#pragma unroll
        for (int m = 0; m < 4; m++)
#pragma unroll
            for (int nn = 0; nn < 2; nn++)
                acc[m][nn] = __builtin_amdgcn_mfma_f32_16x16x32_bf16(Af[m], Bf[nn][ks], acc[m][nn], 0, 0, 0);
    }

    // epilogue: C/D layout col=lane&15, row=quad*4+reg
#pragma unroll
    for (int m = 0; m < 4; m++) {
        int ib = m * 16 + q * 4;
#pragma unroll
        for (int nn = 0; nn < 2; nn++) {
            int o = (wave * 2 + nn) * 16 + l16;
#pragma unroll
            for (int rg = 0; rg < 4; rg++) {
                int i = ib + rg;
                float g = 1.0f / (1.0f + __expf(-acc[m][nn][rg]));
                float sh = bf2f(Xs[i * XPITCH + DIM + o]);
                Ms[i * MPITCH + o] = f2bf(sh * att_s[i] * g);
            }
        }
    }
    __syncthreads();
#pragma unroll
    for (int u = 0; u < 4; u++) {
        int v = u * 256 + t;
        int i = v >> 4;       // row
        int c = v & 15;       // 16B chunk
        if (!val_s[i]) continue;
        short8 val = *(const short8*)&Ms[i * MPITCH + c * 8];
        *(short8*)&msgbuf[(size_t)pos_s[i] * DIM + c * 8] = val;
    }
}

// ---------------- segment-sum (sequential stream) -> hN bf16 ----------------
__global__ __launch_bounds__(256) void k_aggr(const unsigned short* __restrict__ msgbuf,
                                              const int* __restrict__ row_ptr,
                                              unsigned short* __restrict__ hN16) {
    int n = blockIdx.x * 4 + (threadIdx.x >> 6);
    int lane = threadIdx.x & 63;
    if (n >= NNODES) return;
    int p0 = row_ptr[n], p1 = row_ptr[n + 1];
    float a0 = 0.0f, a1 = 0.0f;
    for (int p = p0; p < p1; p++) {
        unsigned v = *(const unsigned*)&msgbuf[(size_t)p * DIM + lane * 2];
        a0 += bf2f((unsigned short)(v & 0xFFFFu));
        a1 += bf2f((unsigned short)(v >> 16));
    }
    unsigned o = (unsigned)f2bf(a0) | ((unsigned)f2bf(a1) << 16);
    *(unsigned*)&hN16[(size_t)n * DIM + lane * 2] = o;
}

// ---------------- out = leaky(W_lin @ [h ; h_N] + b) via MFMA ----------------
__global__ __launch_bounds__(256) void k_out(const unsigned short* __restrict__ h16,
                                             const unsigned short* __restrict__ hN16,
                                             const unsigned short* __restrict__ Wl,
                                             const float* __restrict__ b_lin,
                                             float* __restrict__ out) {
    __shared__ unsigned short Xs[EPB * XPITCH];
    const int t = threadIdx.x;
    const int nb = blockIdx.x * 64;

#pragma unroll
    for (int u = 0; u < 8; u++) {
        int v = u * 256 + t;
        int i = v >> 5;
        int c = v & 31;
        int n = nb + i;
        if (n >= NNODES) n = NNODES - 1;
        const unsigned short* srcp = (c < 16) ? h16 : hN16;
        *(short8*)&Xs[i * XPITCH + c * 8] = *(const short8*)&srcp[(size_t)n * DIM + (c & 15) * 8];
    }

    const int wave = t >> 6;
    const int lane = t & 63;
    const int q = lane >> 4;
    const int l16 = lane & 15;

    short8 Bf[2][8];
#pragma unroll
    for (int nn = 0; nn < 2; nn++) {
        int o = (wave * 2 + nn) * 16 + l16;
        const unsigned short* bp = Wl + (size_t)o * TWOD + q * 8;
#pragma unroll
        for (int ks = 0; ks < 8; ks++) Bf[nn][ks] = *(const short8*)(bp + ks * 32);
    }

    __syncthreads();

    floatx4 acc[4][2];
#pragma unroll
    for (int m = 0; m < 4; m++)
#pragma unroll
        for (int nn = 0; nn < 2; nn++) acc[m][nn] = (floatx4)(0.0f);

#pragma unroll
    for (int ks = 0; ks < 8; ks++) {
        short8 Af[4];
        const unsigned short* xb = &Xs[l16 * XPITCH + ks * 32 + q * 8];
#pragma unroll
        for (int m = 0; m < 4; m++) Af[m] = *(const short8*)(xb + m * 16 * XPITCH);
#pragma unroll
        for (int m = 0; m < 4; m++)
#pragma unroll
            for (int nn = 0; nn < 2; nn++)
                acc[m][nn] = __builtin_amdgcn_mfma_f32_16x16x32_bf16(Af[m], Bf[nn][ks], acc[m][nn], 0, 0, 0);
    }

#pragma unroll
    for (int m = 0; m < 4; m++) {
        int ib = m * 16 + q * 4;
#pragma unroll
        for (int nn = 0; nn < 2; nn++) {
            int o = (wave * 2 + nn) * 16 + l16;
            float bl = b_lin[o];
#pragma unroll
            for (int rg = 0; rg < 4; rg++) {
                int n = nb + ib + rg;
                if (n < NNODES) {
                    float val = acc[m][nn][rg] + bl;
                    val = val > 0.0f ? val : SLOPE * val;
                    out[(size_t)n * DIM + o] = val;
                }
            }
        }
    }
}

// ---------------- launcher ----------------
extern "C" void kernel_launch(void* const* d_in, const int* in_sizes, int n_in,
                              void* d_out, int out_size, void* d_ws, size_t ws_size,
                              hipStream_t stream) {
    const float* h     = (const float*)d_in[0];
    const float* rel   = (const float*)d_in[1];
    const float* ratt  = (const float*)d_in[2];
    const float* W_a   = (const float*)d_in[3];
    const float* b_a   = (const float*)d_in[4];
    const float* W_lin = (const float*)d_in[5];
    const float* b_lin = (const float*)d_in[6];
    const int* src = (const int*)d_in[7];
    const int* dst = (const int*)d_in[8];
    const int* ety = (const int*)d_in[9];
    float* out = (float*)d_out;

    // workspace layout (~176 MB; round-4 evidence shows ws >= ~189 MB)
    float* scoreP = (float*)d_ws;                                   // E  (doubles as attP)
    unsigned short* h16    = (unsigned short*)(scoreP + NEDGES);    // N*128 bf16
    unsigned short* proj16 = h16 + (size_t)NNODES * DIM;            // N*128 bf16
    unsigned short* hN16   = proj16 + (size_t)NNODES * DIM;         // N*128 bf16
    unsigned short* relT   = hN16 + (size_t)NNODES * DIM;           // 8*128*256 bf16
    unsigned short* Wl     = relT + (size_t)NRELS * DIM * TWOD;     // 128*256 bf16
    unsigned short* Wa2    = Wl + (size_t)DIM * TWOD;               // 128*128 bf16
    int* srcS    = (int*)(Wa2 + (size_t)DIM * DIM);                 // SPAD
    int* dstS    = srcS + SPAD;                                     // SPAD
    int* posS    = dstS + SPAD;                                     // SPAD
    int* row_ptr = posS + SPAD;                                     // N+1
    int* histD   = row_ptr + (NNODES + 1);                          // N
    int* cursorD = histD + NNODES;                                  // N
    int* cnts    = cursorD + NNODES;                                // 16 (cnt[8] + cursorE[8])
    int* offs    = cnts + 16;                                       // 8
    unsigned short* msgbuf = (unsigned short*)(((uintptr_t)(offs + 8) + 255) & ~(uintptr_t)255); // E*128 bf16

    k_init<<<2048, 256, 0, stream>>>(srcS, histD, cursorD, cnts);
    k_prep<<<(NRELS * TWOD * DIM + DIM * TWOD + DIM * DIM + 255) / 256, 256, 0, stream>>>(
        rel, W_lin, W_a, relT, Wl, Wa2);
    k_h16<<<(NNODES * DIM / 8 + 255) / 256, 256, 0, stream>>>(h, h16);
    k_hist2<<<(NEDGES + 255) / 256, 256, 0, stream>>>(ety, dst, cnts, histD);
    k_scan<<<1, 1024, 0, stream>>>(histD, row_ptr, cnts, offs);
    k_scatter2<<<(NEDGES + 255) / 256, 256, 0, stream>>>(
        ety, src, dst, offs, row_ptr, cnts + 8, cursorD, srcS, dstS, posS);
    k_nodeproj<<<(NNODES + 63) / 64, 256, 0, stream>>>(h16, Wa2, proj16);
    k_score<<<(NEDGES + 8 * EPB + 3) / 4, 256, 0, stream>>>(
        proj16, b_a, ratt, srcS, dstS, posS, scoreP);
    k_segsoft<<<(NNODES + 3) / 4, 256, 0, stream>>>(scoreP, row_ptr);
    k_gate_msg<<<(NEDGES + 8 * EPB + EPB - 1) / EPB, 256, 0, stream>>>(
        h16, relT, srcS, dstS, posS, scoreP, offs, msgbuf);
    k_aggr<<<(NNODES + 3) / 4, 256, 0, stream>>>(msgbuf, row_ptr, hN16);
    k_out<<<(NNODES + 63) / 64, 256, 0, stream>>>(h16, hN16, Wl, b_lin, out);
}

// Round 7
// 553.784 us; speedup vs baseline: 1.2483x; 1.0564x over previous
//
#include <hip/hip_runtime.h>
#include <cstdint>
#include <cstddef>

// ---------------- problem constants ----------------
constexpr int NNODES = 50000;
constexpr int NEDGES = 500000;
constexpr int NRELS  = 8;
constexpr int DIM    = 128;
constexpr int ADIM   = 64;
constexpr int TWOD   = 256;
constexpr int EPB    = 64;
constexpr float SLOPE = 0.01f;

constexpr int XPITCH = TWOD + 8;
constexpr int PPITCH = DIM + 8;
constexpr int MPITCH = DIM + 8;
constexpr int SPAD = NEDGES + 1024;

typedef __attribute__((ext_vector_type(8))) short short8;
typedef __attribute__((ext_vector_type(4))) float floatx4;

__device__ __forceinline__ unsigned short f2bf(float f) {
    unsigned u = __float_as_uint(f);
    unsigned r = u + 0x7FFFu + ((u >> 16) & 1u);
    return (unsigned short)(r >> 16);
}
__device__ __forceinline__ float bf2f(unsigned short b) {
    return __uint_as_float(((unsigned)b) << 16);
}

// ---------------- init ----------------
__global__ void k_init(int* __restrict__ srcS, int* __restrict__ histD,
                       int* __restrict__ cursorD, int* __restrict__ cnts) {
    int i = blockIdx.x * blockDim.x + threadIdx.x;
    int stride = gridDim.x * blockDim.x;
    for (int idx = i; idx < SPAD; idx += stride) srcS[idx] = -1;
    for (int idx = i; idx < NNODES; idx += stride) { histD[idx] = 0; cursorD[idx] = 0; }
    if (i < 16) cnts[i] = 0;
}

// ---------------- prep: relT transpose via LDS tile; Wl/Wa2 linear ----------------
__global__ __launch_bounds__(256) void k_prep(const float* __restrict__ rel,
                                              const float* __restrict__ W_lin,
                                              const float* __restrict__ W_a,
                                              unsigned short* __restrict__ relT,
                                              unsigned short* __restrict__ Wl,
                                              unsigned short* __restrict__ Wa2) {
    __shared__ float ls[64][65];
    int b = blockIdx.x, t = threadIdx.x;
    if (b < 64) {
        // transpose one 64(d) x 64(o) tile of rel[r] into relT[r][o][d]
        int r = b >> 3, tile = b & 7;
        int d0 = (tile >> 1) * 64, o0 = (tile & 1) * 64;
        const float* rp = rel + ((size_t)r * TWOD + d0) * DIM + o0;
#pragma unroll
        for (int u = 0; u < 16; u++) {
            int v = u * 256 + t;
            int j = v & 63, i = v >> 6;       // j = o (coalesced), i = d
            ls[i][j] = rp[(size_t)i * DIM + j];
        }
        __syncthreads();
        unsigned short* wp = relT + ((size_t)r * DIM + o0) * TWOD + d0;
#pragma unroll
        for (int u = 0; u < 16; u++) {
            int v = u * 256 + t;
            int ii = v & 63, jj = v >> 6;     // ii = d (coalesced write), jj = o
            wp[(size_t)jj * TWOD + ii] = f2bf(ls[ii][jj]);
        }
    } else {
        int idx = (b - 64) * 256 + t;
        if (idx < DIM * TWOD) {
            Wl[idx] = f2bf(W_lin[idx]);
        } else {
            int j = idx - DIM * TWOD;
            if (j < DIM * DIM) {
                int d = j & 127, o = j >> 7;
                float v = (o < ADIM) ? W_a[(size_t)o * TWOD + d]
                                     : W_a[(size_t)(o - ADIM) * TWOD + DIM + d];
                Wa2[j] = f2bf(v);
            }
        }
    }
}

// ---------------- fused histogram: etype counts + dst histogram ----------------
__global__ void k_hist2(const int* __restrict__ ety, const int* __restrict__ dst,
                        int* __restrict__ cnt, int* __restrict__ histD) {
    __shared__ int hist[NRELS];
    int t = threadIdx.x;
    if (t < NRELS) hist[t] = 0;
    __syncthreads();
    int e = blockIdx.x * 256 + t;
    if (e < NEDGES) {
        atomicAdd(&hist[ety[e]], 1);
        atomicAdd(&histD[dst[e]], 1);
    }
    __syncthreads();
    if (t < NRELS && hist[t] > 0) atomicAdd(&cnt[t], hist[t]);
}

// ---------------- scan: dst row_ptr + etype bucket offsets ----------------
__global__ __launch_bounds__(1024) void k_scan(const int* __restrict__ histD,
                                               int* __restrict__ row_ptr,
                                               const int* __restrict__ cnt,
                                               int* __restrict__ offs) {
    __shared__ int ls[1024];
    const int t = threadIdx.x;
    const int CH = (NNODES + 1023) / 1024;
    const int base = t * CH;
    int s = 0;
    for (int j = 0; j < CH; j++) { int i = base + j; if (i < NNODES) s += histD[i]; }
    ls[t] = s;
    __syncthreads();
    for (int off = 1; off < 1024; off <<= 1) {
        int v = (t >= off) ? ls[t - off] : 0;
        __syncthreads();
        ls[t] += v;
        __syncthreads();
    }
    int run = (t == 0) ? 0 : ls[t - 1];
    for (int j = 0; j < CH; j++) {
        int i = base + j;
        if (i < NNODES) { row_ptr[i] = run; run += histD[i]; }
    }
    if (t == 1023) row_ptr[NNODES] = ls[1023];
    if (t == 0) {
        int off = 0;
        for (int r = 0; r < NRELS; r++) {
            offs[r] = off;
            off += ((cnt[r] + EPB - 1) / EPB) * EPB;
        }
    }
}

// ---------------- scatter into dst-CSR order: srcP/dstP/etyP indexed by p ----------------
__global__ void k_dscatter(const int* __restrict__ ety, const int* __restrict__ src,
                           const int* __restrict__ dst, const int* __restrict__ row_ptr,
                           int* __restrict__ cursorD,
                           int* __restrict__ srcP, int* __restrict__ dstP,
                           int* __restrict__ etyP) {
    int e = blockIdx.x * 256 + threadIdx.x;
    if (e < NEDGES) {
        int dn = dst[e];
        int pos = row_ptr[dn] + atomicAdd(&cursorD[dn], 1);
        srcP[pos] = src[e];
        dstP[pos] = dn;
        etyP[pos] = ety[e];
    }
}

// ---------------- scatter p-order -> etype buckets (dst-clustered within buckets) ----------------
__global__ void k_scatter3(const int* __restrict__ srcP, const int* __restrict__ dstP,
                           const int* __restrict__ etyP, const int* __restrict__ offs,
                           int* __restrict__ cursorE,
                           int* __restrict__ srcS, int* __restrict__ dstS,
                           int* __restrict__ posS) {
    __shared__ int hist[NRELS];
    __shared__ int basew[NRELS];
    int t = threadIdx.x;
    if (t < NRELS) hist[t] = 0;
    __syncthreads();
    int p = blockIdx.x * 256 + t;
    int r = -1, rank = 0, sn = 0, dn = 0;
    if (p < NEDGES) {
        r = etyP[p]; sn = srcP[p]; dn = dstP[p];
        rank = atomicAdd(&hist[r], 1);
    }
    __syncthreads();
    if (t < NRELS && hist[t] > 0) basew[t] = atomicAdd(&cursorE[t], hist[t]);
    __syncthreads();
    if (p < NEDGES) {
        int s = offs[r] + basew[r] + rank;
        srcS[s] = sn;
        dstS[s] = dn;
        posS[s] = p;
    }
}

// ---------------- nodeproj via MFMA; also emits h16 ----------------
__global__ __launch_bounds__(256) void k_nodeproj(const float* __restrict__ h,
                                                  const unsigned short* __restrict__ Wa2,
                                                  unsigned short* __restrict__ proj16,
                                                  unsigned short* __restrict__ h16) {
    __shared__ unsigned short Xs[EPB * PPITCH];
    const int t = threadIdx.x;
    const int nb = blockIdx.x * 64;

#pragma unroll
    for (int u = 0; u < 4; u++) {
        int v = u * 256 + t;
        int i = v >> 4;
        int c = v & 15;
        int n = nb + i;
        bool ok = n < NNODES;
        if (!ok) n = NNODES - 1;
        const float4* hp = (const float4*)(h + (size_t)n * DIM + c * 8);
        float4 a = hp[0], b = hp[1];
        union { unsigned short us[8]; short8 s8; } pk;
        pk.us[0] = f2bf(a.x); pk.us[1] = f2bf(a.y); pk.us[2] = f2bf(a.z); pk.us[3] = f2bf(a.w);
        pk.us[4] = f2bf(b.x); pk.us[5] = f2bf(b.y); pk.us[6] = f2bf(b.z); pk.us[7] = f2bf(b.w);
        *(short8*)&Xs[i * PPITCH + c * 8] = pk.s8;
        if (ok) *(short8*)&h16[(size_t)n * DIM + c * 8] = pk.s8;
    }

    const int wave = t >> 6;
    const int lane = t & 63;
    const int q = lane >> 4;
    const int l16 = lane & 15;

    short8 Bf[2][4];
#pragma unroll
    for (int nn = 0; nn < 2; nn++) {
        int o = (wave * 2 + nn) * 16 + l16;
        const unsigned short* bp = Wa2 + (size_t)o * DIM + q * 8;
#pragma unroll
        for (int ks = 0; ks < 4; ks++) Bf[nn][ks] = *(const short8*)(bp + ks * 32);
    }

    __syncthreads();

    floatx4 acc[4][2];
#pragma unroll
    for (int m = 0; m < 4; m++)
#pragma unroll
        for (int nn = 0; nn < 2; nn++) acc[m][nn] = (floatx4)(0.0f);

#pragma unroll
    for (int ks = 0; ks < 4; ks++) {
        short8 Af[4];
        const unsigned short* xb = &Xs[l16 * PPITCH + ks * 32 + q * 8];
#pragma unroll
        for (int m = 0; m < 4; m++) Af[m] = *(const short8*)(xb + m * 16 * PPITCH);
#pragma unroll
        for (int m = 0; m < 4; m++)
#pragma unroll
            for (int nn = 0; nn < 2; nn++)
                acc[m][nn] = __builtin_amdgcn_mfma_f32_16x16x32_bf16(Af[m], Bf[nn][ks], acc[m][nn], 0, 0, 0);
    }

#pragma unroll
    for (int m = 0; m < 4; m++) {
        int ib = m * 16 + q * 4;
#pragma unroll
        for (int nn = 0; nn < 2; nn++) {
            int o = (wave * 2 + nn) * 16 + l16;
#pragma unroll
            for (int rg = 0; rg < 4; rg++) {
                int n = nb + ib + rg;
                if (n < NNODES) proj16[(size_t)n * DIM + o] = f2bf(acc[m][nn][rg]);
            }
        }
    }
}

// ---------------- score in p-order (dst-sorted): coalesced meta, clustered dst reads ----------------
__global__ __launch_bounds__(256) void k_score(const unsigned short* __restrict__ proj16,
                                               const float* __restrict__ b_a, const float* __restrict__ ratt,
                                               const int* __restrict__ srcP, const int* __restrict__ dstP,
                                               float* __restrict__ scoreP) {
    int p = blockIdx.x * 4 + (threadIdx.x >> 6);
    int lane = threadIdx.x & 63;
    if (p >= NEDGES) return;
    int sn = srcP[p], dn = dstP[p];
    float v = bf2f(proj16[(size_t)dn * DIM + lane]) + bf2f(proj16[(size_t)sn * DIM + ADIM + lane]) + b_a[lane];
    v = v > 0.0f ? v : SLOPE * v;
    v *= ratt[lane];
#pragma unroll
    for (int off = 32; off > 0; off >>= 1) v += __shfl_down(v, off);
    if (lane == 0) scoreP[p] = v;
}

// ---------------- segment softmax, 16-lane groups (4 nodes per wave) ----------------
__global__ __launch_bounds__(256) void k_segsoft(float* __restrict__ scoreP,
                                                 const int* __restrict__ row_ptr) {
    int n = blockIdx.x * 16 + (threadIdx.x >> 4);
    int l = threadIdx.x & 15;
    if (n >= NNODES) return;
    int p0 = row_ptr[n], p1 = row_ptr[n + 1];
    if (p0 >= p1) return;
    float m = -3.0e38f;
    for (int p = p0 + l; p < p1; p += 16) m = fmaxf(m, scoreP[p]);
#pragma unroll
    for (int off = 8; off > 0; off >>= 1) m = fmaxf(m, __shfl_xor(m, off, 16));
    float sum = 0.0f;
    for (int p = p0 + l; p < p1; p += 16) {
        float x = __expf(scoreP[p] - m);
        scoreP[p] = x;
        sum += x;
    }
#pragma unroll
    for (int off = 8; off > 0; off >>= 1) sum += __shfl_xor(sum, off, 16);
    float inv = 1.0f / sum;
    for (int p = p0 + l; p < p1; p += 16) scoreP[p] *= inv;
}

// ---------------- gates + messages via MFMA (attn applied later in k_aggr) ----------------
__global__ __launch_bounds__(256) void k_gate_msg(
    const unsigned short* __restrict__ h16, const unsigned short* __restrict__ relT,
    const int* __restrict__ srcS, const int* __restrict__ dstS, const int* __restrict__ posS,
    const int* __restrict__ offs,
    unsigned short* __restrict__ msgbuf) {
    __shared__ unsigned short Xs[EPB * XPITCH];
    __shared__ unsigned short Ms[EPB * MPITCH];
    __shared__ int srcn_s[EPB];
    __shared__ int dstn_s[EPB];
    __shared__ int pos_s[EPB];
    __shared__ int val_s[EPB];

    const int t = threadIdx.x;
    const int base = blockIdx.x * EPB;

    if (t < EPB) {
        int s = base + t;
        int sv = srcS[s];
        int valid = sv >= 0;
        val_s[t] = valid;
        srcn_s[t] = valid ? sv : 0;
        dstn_s[t] = valid ? dstS[s] : 0;
        pos_s[t] = valid ? posS[s] : 0;
    }
    __syncthreads();
    if (!val_s[0]) return;

    int r = 0;
#pragma unroll
    for (int i = 1; i < NRELS; i++) if (base >= offs[i]) r = i;

#pragma unroll
    for (int u = 0; u < 8; u++) {
        int v = u * 256 + t;
        int i = v >> 5;
        int c = v & 31;
        int node = (c < 16) ? dstn_s[i] : srcn_s[i];
        *(short8*)&Xs[i * XPITCH + c * 8] = *(const short8*)&h16[(size_t)node * DIM + (c & 15) * 8];
    }

    const int wave = t >> 6;
    const int lane = t & 63;
    const int q = lane >> 4;
    const int l16 = lane & 15;

    short8 Bf[2][8];
#pragma unroll
    for (int nn = 0; nn < 2; nn++) {
        int o = (wave * 2 + nn) * 16 + l16;
        const unsigned short* bp = relT + ((size_t)r * DIM + o) * TWOD + q * 8;
#pragma unroll
        for (int ks = 0; ks < 8; ks++) Bf[nn][ks] = *(const short8*)(bp + ks * 32);
    }

    __syncthreads();

    floatx4 acc[4][2];
#pragma unroll
    for (int m = 0; m < 4; m++)
#pragma unroll
        for (int nn = 0; nn < 2; nn++) acc[m][nn] = (floatx4)(0.0f);

#pragma unroll
    for (int ks = 0; ks < 8; ks++) {
        short8 Af[4];
        const unsigned short* xb = &Xs[l16 * XPITCH + ks * 32 + q * 8];
#pragma unroll
        for (int m = 0; m < 4; m++) Af[m] = *(const short8*)(xb + m * 16 * XPITCH);
#pragma unroll
        for (int m = 0; m < 4; m++)
#pragma unroll
            for (int nn = 0; nn < 2; nn++)
                acc[m][nn] = __builtin_amdgcn_mfma_f32_16x16x32_bf16(Af[m], Bf[nn][ks], acc[m][nn], 0, 0, 0);
    }

#pragma unroll
    for (int m = 0; m < 4; m++) {
        int ib = m * 16 + q * 4;
#pragma unroll
        for (int nn = 0; nn < 2; nn++) {
            int o = (wave * 2 + nn) * 16 + l16;
#pragma unroll
            for (int rg = 0; rg < 4; rg++) {
                int i = ib + rg;
                float g = 1.0f / (1.0f + __expf(-acc[m][nn][rg]));
                float sh = bf2f(Xs[i * XPITCH + DIM + o]);
                Ms[i * MPITCH + o] = f2bf(sh * g);
            }
        }
    }
    __syncthreads();
#pragma unroll
    for (int u = 0; u < 4; u++) {
        int v = u * 256 + t;
        int i = v >> 4;
        int c = v & 15;
        if (!val_s[i]) continue;
        short8 val = *(const short8*)&Ms[i * MPITCH + c * 8];
        *(short8*)&msgbuf[(size_t)pos_s[i] * DIM + c * 8] = val;
    }
}

// ---------------- segment-sum with attention (sequential stream) -> hN bf16 ----------------
__global__ __launch_bounds__(256) void k_aggr(const unsigned short* __restrict__ msgbuf,
                                              const float* __restrict__ attP,
                                              const int* __restrict__ row_ptr,
                                              unsigned short* __restrict__ hN16) {
    int n = blockIdx.x * 4 + (threadIdx.x >> 6);
    int lane = threadIdx.x & 63;
    if (n >= NNODES) return;
    int p0 = row_ptr[n], p1 = row_ptr[n + 1];
    float a0 = 0.0f, a1 = 0.0f;
    for (int p = p0; p < p1; p++) {
        float at = attP[p];
        unsigned v = *(const unsigned*)&msgbuf[(size_t)p * DIM + lane * 2];
        a0 += at * bf2f((unsigned short)(v & 0xFFFFu));
        a1 += at * bf2f((unsigned short)(v >> 16));
    }
    unsigned o = (unsigned)f2bf(a0) | ((unsigned)f2bf(a1) << 16);
    *(unsigned*)&hN16[(size_t)n * DIM + lane * 2] = o;
}

// ---------------- out = leaky(W_lin @ [h ; h_N] + b) via MFMA ----------------
__global__ __launch_bounds__(256) void k_out(const unsigned short* __restrict__ h16,
                                             const unsigned short* __restrict__ hN16,
                                             const unsigned short* __restrict__ Wl,
                                             const float* __restrict__ b_lin,
                                             float* __restrict__ out) {
    __shared__ unsigned short Xs[EPB * XPITCH];
    const int t = threadIdx.x;
    const int nb = blockIdx.x * 64;

#pragma unroll
    for (int u = 0; u < 8; u++) {
        int v = u * 256 + t;
        int i = v >> 5;
        int c = v & 31;
        int n = nb + i;
        if (n >= NNODES) n = NNODES - 1;
        const unsigned short* srcp = (c < 16) ? h16 : hN16;
        *(short8*)&Xs[i * XPITCH + c * 8] = *(const short8*)&srcp[(size_t)n * DIM + (c & 15) * 8];
    }

    const int wave = t >> 6;
    const int lane = t & 63;
    const int q = lane >> 4;
    const int l16 = lane & 15;

    short8 Bf[2][8];
#pragma unroll
    for (int nn = 0; nn < 2; nn++) {
        int o = (wave * 2 + nn) * 16 + l16;
        const unsigned short* bp = Wl + (size_t)o * TWOD + q * 8;
#pragma unroll
        for (int ks = 0; ks < 8; ks++) Bf[nn][ks] = *(const short8*)(bp + ks * 32);
    }

    __syncthreads();

    floatx4 acc[4][2];
#pragma unroll
    for (int m = 0; m < 4; m++)
#pragma unroll
        for (int nn = 0; nn < 2; nn++) acc[m][nn] = (floatx4)(0.0f);

#pragma unroll
    for (int ks = 0; ks < 8; ks++) {
        short8 Af[4];
        const unsigned short* xb = &Xs[l16 * XPITCH + ks * 32 + q * 8];
#pragma unroll
        for (int m = 0; m < 4; m++) Af[m] = *(const short8*)(xb + m * 16 * XPITCH);
#pragma unroll
        for (int m = 0; m < 4; m++)
#pragma unroll
            for (int nn = 0; nn < 2; nn++)
                acc[m][nn] = __builtin_amdgcn_mfma_f32_16x16x32_bf16(Af[m], Bf[nn][ks], acc[m][nn], 0, 0, 0);
    }

#pragma unroll
    for (int m = 0; m < 4; m++) {
        int ib = m * 16 + q * 4;
#pragma unroll
        for (int nn = 0; nn < 2; nn++) {
            int o = (wave * 2 + nn) * 16 + l16;
            float bl = b_lin[o];
#pragma unroll
            for (int rg = 0; rg < 4; rg++) {
                int n = nb + ib + rg;
                if (n < NNODES) {
                    float val = acc[m][nn][rg] + bl;
                    val = val > 0.0f ? val : SLOPE * val;
                    out[(size_t)n * DIM + o] = val;
                }
            }
        }
    }
}

// ---------------- launcher ----------------
extern "C" void kernel_launch(void* const* d_in, const int* in_sizes, int n_in,
                              void* d_out, int out_size, void* d_ws, size_t ws_size,
                              hipStream_t stream) {
    const float* h     = (const float*)d_in[0];
    const float* rel   = (const float*)d_in[1];
    const float* ratt  = (const float*)d_in[2];
    const float* W_a   = (const float*)d_in[3];
    const float* b_a   = (const float*)d_in[4];
    const float* W_lin = (const float*)d_in[5];
    const float* b_lin = (const float*)d_in[6];
    const int* src = (const int*)d_in[7];
    const int* dst = (const int*)d_in[8];
    const int* ety = (const int*)d_in[9];
    float* out = (float*)d_out;

    // workspace layout (~182 MB; round-4 evidence: ws >= ~189 MB)
    float* scoreP = (float*)d_ws;                                   // E (also attP after softmax)
    unsigned short* h16    = (unsigned short*)(scoreP + NEDGES);    // N*128 bf16
    unsigned short* proj16 = h16 + (size_t)NNODES * DIM;            // N*128 bf16
    unsigned short* hN16   = proj16 + (size_t)NNODES * DIM;         // N*128 bf16
    unsigned short* relT   = hN16 + (size_t)NNODES * DIM;           // 8*128*256 bf16
    unsigned short* Wl     = relT + (size_t)NRELS * DIM * TWOD;     // 128*256 bf16
    unsigned short* Wa2    = Wl + (size_t)DIM * TWOD;               // 128*128 bf16
    int* srcS    = (int*)(Wa2 + (size_t)DIM * DIM);                 // SPAD
    int* dstS    = srcS + SPAD;                                     // SPAD
    int* posS    = dstS + SPAD;                                     // SPAD
    int* srcP    = posS + SPAD;                                     // E
    int* dstP    = srcP + NEDGES;                                   // E
    int* etyP    = dstP + NEDGES;                                   // E
    int* row_ptr = etyP + NEDGES;                                   // N+1
    int* histD   = row_ptr + (NNODES + 1);                          // N
    int* cursorD = histD + NNODES;                                  // N
    int* cnts    = cursorD + NNODES;                                // 16 (cnt[8] + cursorE[8])
    int* offs    = cnts + 16;                                       // 8
    unsigned short* msgbuf = (unsigned short*)(((uintptr_t)(offs + 8) + 255) & ~(uintptr_t)255); // E*128 bf16

    k_init<<<2048, 256, 0, stream>>>(srcS, histD, cursorD, cnts);
    k_prep<<<64 + (DIM * TWOD + DIM * DIM + 255) / 256, 256, 0, stream>>>(
        rel, W_lin, W_a, relT, Wl, Wa2);
    k_hist2<<<(NEDGES + 255) / 256, 256, 0, stream>>>(ety, dst, cnts, histD);
    k_scan<<<1, 1024, 0, stream>>>(histD, row_ptr, cnts, offs);
    k_dscatter<<<(NEDGES + 255) / 256, 256, 0, stream>>>(
        ety, src, dst, row_ptr, cursorD, srcP, dstP, etyP);
    k_nodeproj<<<(NNODES + 63) / 64, 256, 0, stream>>>(h, Wa2, proj16, h16);
    k_scatter3<<<(NEDGES + 255) / 256, 256, 0, stream>>>(
        srcP, dstP, etyP, offs, cnts + 8, srcS, dstS, posS);
    k_score<<<(NEDGES + 3) / 4, 256, 0, stream>>>(proj16, b_a, ratt, srcP, dstP, scoreP);
    k_segsoft<<<(NNODES + 15) / 16, 256, 0, stream>>>(scoreP, row_ptr);
    k_gate_msg<<<(NEDGES + 8 * EPB + EPB - 1) / EPB, 256, 0, stream>>>(
        h16, relT, srcS, dstS, posS, offs, msgbuf);
    k_aggr<<<(NNODES + 3) / 4, 256, 0, stream>>>(msgbuf, scoreP, row_ptr, hN16);
    k_out<<<(NNODES + 63) / 64, 256, 0, stream>>>(h16, hN16, Wl, b_lin, out);
}

// Round 8
// 547.422 us; speedup vs baseline: 1.2628x; 1.0116x over previous
//
#include <hip/hip_runtime.h>
#include <cstdint>
#include <cstddef>

// ---------------- problem constants ----------------
constexpr int NNODES = 50000;
constexpr int NEDGES = 500000;
constexpr int NRELS  = 8;
constexpr int DIM    = 128;
constexpr int ADIM   = 64;
constexpr int TWOD   = 256;
constexpr int EPB    = 64;
constexpr float SLOPE = 0.01f;

constexpr int XPITCH = TWOD + 8;
constexpr int SPAD = NEDGES + 1024;

typedef __attribute__((ext_vector_type(8))) short short8;
typedef __attribute__((ext_vector_type(4))) float floatx4;

__device__ __forceinline__ unsigned short f2bf(float f) {
    unsigned u = __float_as_uint(f);
    unsigned r = u + 0x7FFFu + ((u >> 16) & 1u);
    return (unsigned short)(r >> 16);
}
__device__ __forceinline__ float bf2f(unsigned short b) {
    return __uint_as_float(((unsigned)b) << 16);
}

// ---------------- init ----------------
__global__ void k_init(int4* __restrict__ sMeta, int* __restrict__ histD,
                       int* __restrict__ cursorD, int* __restrict__ cnts) {
    int i = blockIdx.x * blockDim.x + threadIdx.x;
    int stride = gridDim.x * blockDim.x;
    for (int idx = i; idx < SPAD; idx += stride) sMeta[idx] = make_int4(-1, 0, 0, 0);
    for (int idx = i; idx < NNODES; idx += stride) { histD[idx] = 0; cursorD[idx] = 0; }
    if (i < 16) cnts[i] = 0;
}

// ---------------- prep: relT transpose via LDS tile; Wl/Wa16 linear ----------------
__global__ __launch_bounds__(256) void k_prep(const float* __restrict__ rel,
                                              const float* __restrict__ W_lin,
                                              const float* __restrict__ W_a,
                                              unsigned short* __restrict__ relT,
                                              unsigned short* __restrict__ Wl,
                                              unsigned short* __restrict__ Wa16) {
    __shared__ float ls[64][65];
    int b = blockIdx.x, t = threadIdx.x;
    if (b < 64) {
        // transpose one 64(d) x 64(o) tile of rel[r] into relT[r][o][d]
        int r = b >> 3, tile = b & 7;
        int d0 = (tile >> 1) * 64, o0 = (tile & 1) * 64;
        const float* rp = rel + ((size_t)r * TWOD + d0) * DIM + o0;
#pragma unroll
        for (int u = 0; u < 16; u++) {
            int v = u * 256 + t;
            int j = v & 63, i = v >> 6;
            ls[i][j] = rp[(size_t)i * DIM + j];
        }
        __syncthreads();
        unsigned short* wp = relT + ((size_t)r * DIM + o0) * TWOD + d0;
#pragma unroll
        for (int u = 0; u < 16; u++) {
            int v = u * 256 + t;
            int ii = v & 63, jj = v >> 6;
            wp[(size_t)jj * TWOD + ii] = f2bf(ls[ii][jj]);
        }
    } else {
        int idx = (b - 64) * 256 + t;
        if (idx < DIM * TWOD) {
            Wl[idx] = f2bf(W_lin[idx]);
        } else {
            int j = idx - DIM * TWOD;
            if (j < ADIM * TWOD) Wa16[j] = f2bf(W_a[j]);   // straight copy: W_a is [64][256]
        }
    }
}

// ---------------- h -> bf16 ----------------
__global__ void k_h16(const float* __restrict__ h, unsigned short* __restrict__ h16) {
    int i = blockIdx.x * 256 + threadIdx.x;
    if (i < NNODES * DIM / 8) {
        const float4* hp = (const float4*)(h + (size_t)i * 8);
        float4 a = hp[0], b = hp[1];
        union { unsigned short us[8]; short8 s8; } pk;
        pk.us[0] = f2bf(a.x); pk.us[1] = f2bf(a.y); pk.us[2] = f2bf(a.z); pk.us[3] = f2bf(a.w);
        pk.us[4] = f2bf(b.x); pk.us[5] = f2bf(b.y); pk.us[6] = f2bf(b.z); pk.us[7] = f2bf(b.w);
        *(short8*)&h16[(size_t)i * 8] = pk.s8;
    }
}

// ---------------- fused histogram: etype counts + dst histogram ----------------
__global__ void k_hist2(const int* __restrict__ ety, const int* __restrict__ dst,
                        int* __restrict__ cnt, int* __restrict__ histD) {
    __shared__ int hist[NRELS];
    int t = threadIdx.x;
    if (t < NRELS) hist[t] = 0;
    __syncthreads();
    int e = blockIdx.x * 256 + t;
    if (e < NEDGES) {
        atomicAdd(&hist[ety[e]], 1);
        atomicAdd(&histD[dst[e]], 1);
    }
    __syncthreads();
    if (t < NRELS && hist[t] > 0) atomicAdd(&cnt[t], hist[t]);
}

// ---------------- scan: dst row_ptr + etype bucket offsets ----------------
__global__ __launch_bounds__(1024) void k_scan(const int* __restrict__ histD,
                                               int* __restrict__ row_ptr,
                                               const int* __restrict__ cnt,
                                               int* __restrict__ offs) {
    __shared__ int ls[1024];
    const int t = threadIdx.x;
    const int CH = (NNODES + 1023) / 1024;
    const int base = t * CH;
    int s = 0;
    for (int j = 0; j < CH; j++) { int i = base + j; if (i < NNODES) s += histD[i]; }
    ls[t] = s;
    __syncthreads();
    for (int off = 1; off < 1024; off <<= 1) {
        int v = (t >= off) ? ls[t - off] : 0;
        __syncthreads();
        ls[t] += v;
        __syncthreads();
    }
    int run = (t == 0) ? 0 : ls[t - 1];
    for (int j = 0; j < CH; j++) {
        int i = base + j;
        if (i < NNODES) { row_ptr[i] = run; run += histD[i]; }
    }
    if (t == 1023) row_ptr[NNODES] = ls[1023];
    if (t == 0) {
        int off = 0;
        for (int r = 0; r < NRELS; r++) {
            offs[r] = off;
            off += ((cnt[r] + EPB - 1) / EPB) * EPB;
        }
    }
}

// ---------------- scatter into dst-CSR order: packed meta4[p] = (src,dst,ety,0) ----------------
__global__ void k_dscatter(const int* __restrict__ ety, const int* __restrict__ src,
                           const int* __restrict__ dst, const int* __restrict__ row_ptr,
                           int* __restrict__ cursorD, int4* __restrict__ meta4) {
    int e = blockIdx.x * 256 + threadIdx.x;
    if (e < NEDGES) {
        int dn = dst[e];
        int pos = row_ptr[dn] + atomicAdd(&cursorD[dn], 1);
        meta4[pos] = make_int4(src[e], dn, ety[e], 0);
    }
}

// ---------------- scatter p-order -> etype buckets: sMeta[s] = (src,dst,p,0) ----------------
__global__ void k_scatter3(const int4* __restrict__ meta4, const int* __restrict__ offs,
                           int* __restrict__ cursorE, int4* __restrict__ sMeta) {
    __shared__ int hist[NRELS];
    __shared__ int basew[NRELS];
    int t = threadIdx.x;
    if (t < NRELS) hist[t] = 0;
    __syncthreads();
    int p = blockIdx.x * 256 + t;
    int r = -1, rank = 0;
    int4 m4 = make_int4(0, 0, 0, 0);
    if (p < NEDGES) {
        m4 = meta4[p];
        r = m4.z;
        rank = atomicAdd(&hist[r], 1);
    }
    __syncthreads();
    if (t < NRELS && hist[t] > 0) basew[t] = atomicAdd(&cursorE[t], hist[t]);
    __syncthreads();
    if (p < NEDGES) {
        int s = offs[r] + basew[r] + rank;
        sMeta[s] = make_int4(m4.x, m4.y, p, 0);
    }
}

// ---------------- gates + messages + attention scores via MFMA ----------------
// Pass 1: gate GEMM (128 out, relT).  Pass 2: score GEMM (64 out, Wa16), LDS Af reloaded.
// Msg tile reuses Xs dst half (dead after MFMA passes) -> LDS ~36 KB -> 4 blocks/CU.
__global__ __launch_bounds__(256) void k_gate_msg(
    const unsigned short* __restrict__ h16, const unsigned short* __restrict__ relT,
    const unsigned short* __restrict__ Wa16,
    const int4* __restrict__ sMeta, const float* __restrict__ b_a,
    const float* __restrict__ ratt, const int* __restrict__ offs,
    unsigned short* __restrict__ msgbuf, float* __restrict__ scoreP) {
    __shared__ unsigned short Xs[EPB * XPITCH];   // 33792 B
    __shared__ int srcn_s[EPB];
    __shared__ int dstn_s[EPB];
    __shared__ int pos_s[EPB];
    __shared__ int val_s[EPB];
    __shared__ float scoreW[EPB][4];              // per-wave score partials

    const int t = threadIdx.x;
    const int base = blockIdx.x * EPB;

    if (t < EPB) {
        int4 m4 = sMeta[base + t];
        int valid = m4.x >= 0;
        val_s[t] = valid;
        srcn_s[t] = valid ? m4.x : 0;
        dstn_s[t] = valid ? m4.y : 0;
        pos_s[t] = valid ? m4.z : 0;
    }
    __syncthreads();
    if (!val_s[0]) return;

    int r = 0;
#pragma unroll
    for (int i = 1; i < NRELS; i++) if (base >= offs[i]) r = i;

#pragma unroll
    for (int u = 0; u < 8; u++) {
        int v = u * 256 + t;
        int i = v >> 5;
        int c = v & 31;
        int node = (c < 16) ? dstn_s[i] : srcn_s[i];
        *(short8*)&Xs[i * XPITCH + c * 8] = *(const short8*)&h16[(size_t)node * DIM + (c & 15) * 8];
    }

    const int wave = t >> 6;
    const int lane = t & 63;
    const int q = lane >> 4;
    const int l16 = lane & 15;

    short8 Bf[2][8];
#pragma unroll
    for (int nn = 0; nn < 2; nn++) {
        int o = (wave * 2 + nn) * 16 + l16;
        const unsigned short* bp = relT + ((size_t)r * DIM + o) * TWOD + q * 8;
#pragma unroll
        for (int ks = 0; ks < 8; ks++) Bf[nn][ks] = *(const short8*)(bp + ks * 32);
    }

    __syncthreads();

    // pass 1: gate GEMM
    floatx4 acc[4][2];
#pragma unroll
    for (int m = 0; m < 4; m++)
#pragma unroll
        for (int nn = 0; nn < 2; nn++) acc[m][nn] = (floatx4)(0.0f);

#pragma unroll
    for (int ks = 0; ks < 8; ks++) {
        short8 Af[4];
        const unsigned short* xb = &Xs[l16 * XPITCH + ks * 32 + q * 8];
#pragma unroll
        for (int m = 0; m < 4; m++) Af[m] = *(const short8*)(xb + m * 16 * XPITCH);
#pragma unroll
        for (int m = 0; m < 4; m++)
#pragma unroll
            for (int nn = 0; nn < 2; nn++)
                acc[m][nn] = __builtin_amdgcn_mfma_f32_16x16x32_bf16(Af[m], Bf[nn][ks], acc[m][nn], 0, 0, 0);
    }

    // pass 2: score GEMM (N=64): o16 = wave*16 + l16
    const int o16 = wave * 16 + l16;
    floatx4 accS[4];
#pragma unroll
    for (int m = 0; m < 4; m++) accS[m] = (floatx4)(0.0f);
    {
        const unsigned short* wb = Wa16 + (size_t)o16 * TWOD + q * 8;
#pragma unroll
        for (int ks = 0; ks < 8; ks++) {
            short8 BS = *(const short8*)(wb + ks * 32);
            short8 Af[4];
            const unsigned short* xb = &Xs[l16 * XPITCH + ks * 32 + q * 8];
#pragma unroll
            for (int m = 0; m < 4; m++) Af[m] = *(const short8*)(xb + m * 16 * XPITCH);
#pragma unroll
            for (int m = 0; m < 4; m++)
                accS[m] = __builtin_amdgcn_mfma_f32_16x16x32_bf16(Af[m], BS, accS[m], 0, 0, 0);
        }
    }

    __syncthreads();  // all Xs reads done before overwriting dst half

    // score epilogue: leaky + ratt + reduce over o (16 lanes, then 4 waves via LDS)
    {
        float ba = b_a[o16];
        float ra = ratt[o16];
#pragma unroll
        for (int m = 0; m < 4; m++) {
#pragma unroll
            for (int rg = 0; rg < 4; rg++) {
                float v = accS[m][rg] + ba;
                v = v > 0.0f ? v : SLOPE * v;
                v *= ra;
#pragma unroll
                for (int off = 8; off > 0; off >>= 1) v += __shfl_xor(v, off, 16);
                if (l16 == 0) scoreW[m * 16 + q * 4 + rg][wave] = v;
            }
        }
    }

    // gate epilogue: msg = sigmoid(acc) * src_h  -> Xs dst half (bf16)
#pragma unroll
    for (int m = 0; m < 4; m++) {
        int ib = m * 16 + q * 4;
#pragma unroll
        for (int nn = 0; nn < 2; nn++) {
            int o = (wave * 2 + nn) * 16 + l16;
#pragma unroll
            for (int rg = 0; rg < 4; rg++) {
                int i = ib + rg;
                float g = 1.0f / (1.0f + __expf(-acc[m][nn][rg]));
                float sh = bf2f(Xs[i * XPITCH + DIM + o]);
                Xs[i * XPITCH + o] = f2bf(sh * g);
            }
        }
    }
    __syncthreads();

    // stream msg rows to msgbuf[pos]; write scores
#pragma unroll
    for (int u = 0; u < 4; u++) {
        int v = u * 256 + t;
        int i = v >> 4;
        int c = v & 15;
        if (!val_s[i]) continue;
        short8 val = *(const short8*)&Xs[i * XPITCH + c * 8];
        *(short8*)&msgbuf[(size_t)pos_s[i] * DIM + c * 8] = val;
    }
    if (t < EPB && val_s[t]) {
        scoreP[pos_s[t]] = scoreW[t][0] + scoreW[t][1] + scoreW[t][2] + scoreW[t][3];
    }
}

// ---------------- segment softmax, 16-lane groups ----------------
__global__ __launch_bounds__(256) void k_segsoft(float* __restrict__ scoreP,
                                                 const int* __restrict__ row_ptr) {
    int n = blockIdx.x * 16 + (threadIdx.x >> 4);
    int l = threadIdx.x & 15;
    if (n >= NNODES) return;
    int p0 = row_ptr[n], p1 = row_ptr[n + 1];
    if (p0 >= p1) return;
    float m = -3.0e38f;
    for (int p = p0 + l; p < p1; p += 16) m = fmaxf(m, scoreP[p]);
#pragma unroll
    for (int off = 8; off > 0; off >>= 1) m = fmaxf(m, __shfl_xor(m, off, 16));
    float sum = 0.0f;
    for (int p = p0 + l; p < p1; p += 16) {
        float x = __expf(scoreP[p] - m);
        scoreP[p] = x;
        sum += x;
    }
#pragma unroll
    for (int off = 8; off > 0; off >>= 1) sum += __shfl_xor(sum, off, 16);
    float inv = 1.0f / sum;
    for (int p = p0 + l; p < p1; p += 16) scoreP[p] *= inv;
}

// ---------------- segment-sum with attention -> hN bf16 ----------------
__global__ __launch_bounds__(256) void k_aggr(const unsigned short* __restrict__ msgbuf,
                                              const float* __restrict__ attP,
                                              const int* __restrict__ row_ptr,
                                              unsigned short* __restrict__ hN16) {
    int n = blockIdx.x * 4 + (threadIdx.x >> 6);
    int lane = threadIdx.x & 63;
    if (n >= NNODES) return;
    int p0 = row_ptr[n], p1 = row_ptr[n + 1];
    float a0 = 0.0f, a1 = 0.0f;
    for (int p = p0; p < p1; p++) {
        float at = attP[p];
        unsigned v = *(const unsigned*)&msgbuf[(size_t)p * DIM + lane * 2];
        a0 += at * bf2f((unsigned short)(v & 0xFFFFu));
        a1 += at * bf2f((unsigned short)(v >> 16));
    }
    unsigned o = (unsigned)f2bf(a0) | ((unsigned)f2bf(a1) << 16);
    *(unsigned*)&hN16[(size_t)n * DIM + lane * 2] = o;
}

// ---------------- out = leaky(W_lin @ [h ; h_N] + b) via MFMA ----------------
__global__ __launch_bounds__(256) void k_out(const unsigned short* __restrict__ h16,
                                             const unsigned short* __restrict__ hN16,
                                             const unsigned short* __restrict__ Wl,
                                             const float* __restrict__ b_lin,
                                             float* __restrict__ out) {
    __shared__ unsigned short Xs[EPB * XPITCH];
    const int t = threadIdx.x;
    const int nb = blockIdx.x * 64;

#pragma unroll
    for (int u = 0; u < 8; u++) {
        int v = u * 256 + t;
        int i = v >> 5;
        int c = v & 31;
        int n = nb + i;
        if (n >= NNODES) n = NNODES - 1;
        const unsigned short* srcp = (c < 16) ? h16 : hN16;
        *(short8*)&Xs[i * XPITCH + c * 8] = *(const short8*)&srcp[(size_t)n * DIM + (c & 15) * 8];
    }

    const int wave = t >> 6;
    const int lane = t & 63;
    const int q = lane >> 4;
    const int l16 = lane & 15;

    short8 Bf[2][8];
#pragma unroll
    for (int nn = 0; nn < 2; nn++) {
        int o = (wave * 2 + nn) * 16 + l16;
        const unsigned short* bp = Wl + (size_t)o * TWOD + q * 8;
#pragma unroll
        for (int ks = 0; ks < 8; ks++) Bf[nn][ks] = *(const short8*)(bp + ks * 32);
    }

    __syncthreads();

    floatx4 acc[4][2];
#pragma unroll
    for (int m = 0; m < 4; m++)
#pragma unroll
        for (int nn = 0; nn < 2; nn++) acc[m][nn] = (floatx4)(0.0f);

#pragma unroll
    for (int ks = 0; ks < 8; ks++) {
        short8 Af[4];
        const unsigned short* xb = &Xs[l16 * XPITCH + ks * 32 + q * 8];
#pragma unroll
        for (int m = 0; m < 4; m++) Af[m] = *(const short8*)(xb + m * 16 * XPITCH);
#pragma unroll
        for (int m = 0; m < 4; m++)
#pragma unroll
            for (int nn = 0; nn < 2; nn++)
                acc[m][nn] = __builtin_amdgcn_mfma_f32_16x16x32_bf16(Af[m], Bf[nn][ks], acc[m][nn], 0, 0, 0);
    }

#pragma unroll
    for (int m = 0; m < 4; m++) {
        int ib = m * 16 + q * 4;
#pragma unroll
        for (int nn = 0; nn < 2; nn++) {
            int o = (wave * 2 + nn) * 16 + l16;
            float bl = b_lin[o];
#pragma unroll
            for (int rg = 0; rg < 4; rg++) {
                int n = nb + ib + rg;
                if (n < NNODES) {
                    float val = acc[m][nn][rg] + bl;
                    val = val > 0.0f ? val : SLOPE * val;
                    out[(size_t)n * DIM + o] = val;
                }
            }
        }
    }
}

// ---------------- launcher ----------------
extern "C" void kernel_launch(void* const* d_in, const int* in_sizes, int n_in,
                              void* d_out, int out_size, void* d_ws, size_t ws_size,
                              hipStream_t stream) {
    const float* h     = (const float*)d_in[0];
    const float* rel   = (const float*)d_in[1];
    const float* ratt  = (const float*)d_in[2];
    const float* W_a   = (const float*)d_in[3];
    const float* b_a   = (const float*)d_in[4];
    const float* W_lin = (const float*)d_in[5];
    const float* b_lin = (const float*)d_in[6];
    const int* src = (const int*)d_in[7];
    const int* dst = (const int*)d_in[8];
    const int* ety = (const int*)d_in[9];
    float* out = (float*)d_out;

    // workspace layout (~173 MB; round-4 evidence: ws >= ~189 MB). all segments 16B-multiples.
    float* scoreP = (float*)d_ws;                                   // E (attn after softmax)
    unsigned short* h16  = (unsigned short*)(scoreP + NEDGES);      // N*128 bf16
    unsigned short* hN16 = h16 + (size_t)NNODES * DIM;              // N*128 bf16
    unsigned short* relT = hN16 + (size_t)NNODES * DIM;             // 8*128*256 bf16
    unsigned short* Wl   = relT + (size_t)NRELS * DIM * TWOD;       // 128*256 bf16
    unsigned short* Wa16 = Wl + (size_t)DIM * TWOD;                 // 64*256 bf16
    int4* meta4  = (int4*)(Wa16 + (size_t)ADIM * TWOD);             // E int4
    int4* sMeta  = meta4 + NEDGES;                                  // SPAD int4
    int* row_ptr = (int*)(sMeta + SPAD);                            // N+1
    int* histD   = row_ptr + (NNODES + 1);                          // N
    int* cursorD = histD + NNODES;                                  // N
    int* cnts    = cursorD + NNODES;                                // 16 (cnt[8]+cursorE[8])
    int* offs    = cnts + 16;                                       // 8
    unsigned short* msgbuf = (unsigned short*)(((uintptr_t)(offs + 8) + 255) & ~(uintptr_t)255); // E*128 bf16

    k_init<<<2048, 256, 0, stream>>>(sMeta, histD, cursorD, cnts);
    k_prep<<<64 + (DIM * TWOD + ADIM * TWOD + 255) / 256, 256, 0, stream>>>(
        rel, W_lin, W_a, relT, Wl, Wa16);
    k_h16<<<(NNODES * DIM / 8 + 255) / 256, 256, 0, stream>>>(h, h16);
    k_hist2<<<(NEDGES + 255) / 256, 256, 0, stream>>>(ety, dst, cnts, histD);
    k_scan<<<1, 1024, 0, stream>>>(histD, row_ptr, cnts, offs);
    k_dscatter<<<(NEDGES + 255) / 256, 256, 0, stream>>>(
        ety, src, dst, row_ptr, cursorD, meta4);
    k_scatter3<<<(NEDGES + 255) / 256, 256, 0, stream>>>(meta4, offs, cnts + 8, sMeta);
    k_gate_msg<<<(NEDGES + 8 * EPB + EPB - 1) / EPB, 256, 0, stream>>>(
        h16, relT, Wa16, sMeta, b_a, ratt, offs, msgbuf, scoreP);
    k_segsoft<<<(NNODES + 15) / 16, 256, 0, stream>>>(scoreP, row_ptr);
    k_aggr<<<(NNODES + 3) / 4, 256, 0, stream>>>(msgbuf, scoreP, row_ptr, hN16);
    k_out<<<(NNODES + 63) / 64, 256, 0, stream>>>(h16, hN16, Wl, b_lin, out);
}

// Round 9
// 475.314 us; speedup vs baseline: 1.4544x; 1.1517x over previous
//
#include <hip/hip_runtime.h>
#include <cstdint>
#include <cstddef>

// ---------------- problem constants ----------------
constexpr int NNODES = 50000;
constexpr int NEDGES = 500000;
constexpr int NRELS  = 8;
constexpr int DIM    = 128;
constexpr int ADIM   = 64;
constexpr int TWOD   = 256;
constexpr int EPB    = 64;
constexpr float SLOPE = 0.01f;

constexpr int XPITCH = TWOD + 8;
constexpr int SPAD = NEDGES + 1024;

typedef __attribute__((ext_vector_type(8))) short short8;
typedef __attribute__((ext_vector_type(4))) float floatx4;

__device__ __forceinline__ unsigned short f2bf(float f) {
    unsigned u = __float_as_uint(f);
    unsigned r = u + 0x7FFFu + ((u >> 16) & 1u);
    return (unsigned short)(r >> 16);
}
__device__ __forceinline__ float bf2f(unsigned short b) {
    return __uint_as_float(((unsigned)b) << 16);
}

// ---------------- init ----------------
__global__ void k_init(int4* __restrict__ sMeta, int* __restrict__ histD,
                       int* __restrict__ cursorD, int* __restrict__ cnts) {
    int i = blockIdx.x * blockDim.x + threadIdx.x;
    int stride = gridDim.x * blockDim.x;
    for (int idx = i; idx < SPAD; idx += stride) sMeta[idx] = make_int4(-1, 0, 0, 0);
    for (int idx = i; idx < NNODES; idx += stride) { histD[idx] = 0; cursorD[idx] = 0; }
    if (i < 16) cnts[i] = 0;
}

// ---------------- prep: relT transpose via LDS tile; Wl/Wa16 linear ----------------
__global__ __launch_bounds__(256) void k_prep(const float* __restrict__ rel,
                                              const float* __restrict__ W_lin,
                                              const float* __restrict__ W_a,
                                              unsigned short* __restrict__ relT,
                                              unsigned short* __restrict__ Wl,
                                              unsigned short* __restrict__ Wa16) {
    __shared__ float ls[64][65];
    int b = blockIdx.x, t = threadIdx.x;
    if (b < 64) {
        int r = b >> 3, tile = b & 7;
        int d0 = (tile >> 1) * 64, o0 = (tile & 1) * 64;
        const float* rp = rel + ((size_t)r * TWOD + d0) * DIM + o0;
#pragma unroll
        for (int u = 0; u < 16; u++) {
            int v = u * 256 + t;
            int j = v & 63, i = v >> 6;
            ls[i][j] = rp[(size_t)i * DIM + j];
        }
        __syncthreads();
        unsigned short* wp = relT + ((size_t)r * DIM + o0) * TWOD + d0;
#pragma unroll
        for (int u = 0; u < 16; u++) {
            int v = u * 256 + t;
            int ii = v & 63, jj = v >> 6;
            wp[(size_t)jj * TWOD + ii] = f2bf(ls[ii][jj]);
        }
    } else {
        int idx = (b - 64) * 256 + t;
        if (idx < DIM * TWOD) {
            Wl[idx] = f2bf(W_lin[idx]);
        } else {
            int j = idx - DIM * TWOD;
            if (j < ADIM * TWOD) Wa16[j] = f2bf(W_a[j]);
        }
    }
}

// ---------------- h -> bf16 ----------------
__global__ void k_h16(const float* __restrict__ h, unsigned short* __restrict__ h16) {
    int i = blockIdx.x * 256 + threadIdx.x;
    if (i < NNODES * DIM / 8) {
        const float4* hp = (const float4*)(h + (size_t)i * 8);
        float4 a = hp[0], b = hp[1];
        union { unsigned short us[8]; short8 s8; } pk;
        pk.us[0] = f2bf(a.x); pk.us[1] = f2bf(a.y); pk.us[2] = f2bf(a.z); pk.us[3] = f2bf(a.w);
        pk.us[4] = f2bf(b.x); pk.us[5] = f2bf(b.y); pk.us[6] = f2bf(b.z); pk.us[7] = f2bf(b.w);
        *(short8*)&h16[(size_t)i * 8] = pk.s8;
    }
}

// ---------------- fused histogram ----------------
__global__ void k_hist2(const int* __restrict__ ety, const int* __restrict__ dst,
                        int* __restrict__ cnt, int* __restrict__ histD) {
    __shared__ int hist[NRELS];
    int t = threadIdx.x;
    if (t < NRELS) hist[t] = 0;
    __syncthreads();
    int e = blockIdx.x * 256 + t;
    if (e < NEDGES) {
        atomicAdd(&hist[ety[e]], 1);
        atomicAdd(&histD[dst[e]], 1);
    }
    __syncthreads();
    if (t < NRELS && hist[t] > 0) atomicAdd(&cnt[t], hist[t]);
}

// ---------------- scan ----------------
__global__ __launch_bounds__(1024) void k_scan(const int* __restrict__ histD,
                                               int* __restrict__ row_ptr,
                                               const int* __restrict__ cnt,
                                               int* __restrict__ offs) {
    __shared__ int ls[1024];
    const int t = threadIdx.x;
    const int CH = (NNODES + 1023) / 1024;
    const int base = t * CH;
    int s = 0;
    for (int j = 0; j < CH; j++) { int i = base + j; if (i < NNODES) s += histD[i]; }
    ls[t] = s;
    __syncthreads();
    for (int off = 1; off < 1024; off <<= 1) {
        int v = (t >= off) ? ls[t - off] : 0;
        __syncthreads();
        ls[t] += v;
        __syncthreads();
    }
    int run = (t == 0) ? 0 : ls[t - 1];
    for (int j = 0; j < CH; j++) {
        int i = base + j;
        if (i < NNODES) { row_ptr[i] = run; run += histD[i]; }
    }
    if (t == 1023) row_ptr[NNODES] = ls[1023];
    if (t == 0) {
        int off = 0;
        for (int r = 0; r < NRELS; r++) {
            offs[r] = off;
            off += ((cnt[r] + EPB - 1) / EPB) * EPB;
        }
    }
}

// ---------------- scatter into dst-CSR order ----------------
__global__ void k_dscatter(const int* __restrict__ ety, const int* __restrict__ src,
                           const int* __restrict__ dst, const int* __restrict__ row_ptr,
                           int* __restrict__ cursorD, int4* __restrict__ meta4) {
    int e = blockIdx.x * 256 + threadIdx.x;
    if (e < NEDGES) {
        int dn = dst[e];
        int pos = row_ptr[dn] + atomicAdd(&cursorD[dn], 1);
        meta4[pos] = make_int4(src[e], dn, ety[e], 0);
    }
}

// ---------------- scatter p-order -> etype buckets ----------------
__global__ void k_scatter3(const int4* __restrict__ meta4, const int* __restrict__ offs,
                           int* __restrict__ cursorE, int4* __restrict__ sMeta) {
    __shared__ int hist[NRELS];
    __shared__ int basew[NRELS];
    int t = threadIdx.x;
    if (t < NRELS) hist[t] = 0;
    __syncthreads();
    int p = blockIdx.x * 256 + t;
    int r = -1, rank = 0;
    int4 m4 = make_int4(0, 0, 0, 0);
    if (p < NEDGES) {
        m4 = meta4[p];
        r = m4.z;
        rank = atomicAdd(&hist[r], 1);
    }
    __syncthreads();
    if (t < NRELS && hist[t] > 0) basew[t] = atomicAdd(&cursorE[t], hist[t]);
    __syncthreads();
    if (p < NEDGES) {
        int s = offs[r] + basew[r] + rank;
        sMeta[s] = make_int4(m4.x, m4.y, p, 0);
    }
}

// ---------------- gates + messages + scores: single merged MFMA K-loop ----------------
// Per ks: 4 ds_read_b128 (Af, shared) + 3 global B loads (L2-hot) + 12 MFMA.
// No B preload -> low VGPR -> occupancy back to ~4 blocks/CU.
__global__ __launch_bounds__(256) void k_gate_msg(
    const unsigned short* __restrict__ h16, const unsigned short* __restrict__ relT,
    const unsigned short* __restrict__ Wa16,
    const int4* __restrict__ sMeta, const float* __restrict__ b_a,
    const float* __restrict__ ratt, const int* __restrict__ offs,
    unsigned short* __restrict__ msgbuf, float* __restrict__ scoreP) {
    __shared__ unsigned short Xs[EPB * XPITCH];   // 33792 B
    __shared__ int srcn_s[EPB];
    __shared__ int dstn_s[EPB];
    __shared__ int pos_s[EPB];
    __shared__ int val_s[EPB];
    __shared__ float scoreW[EPB][4];

    const int t = threadIdx.x;
    const int base = blockIdx.x * EPB;

    if (t < EPB) {
        int4 m4 = sMeta[base + t];
        int valid = m4.x >= 0;
        val_s[t] = valid;
        srcn_s[t] = valid ? m4.x : 0;
        dstn_s[t] = valid ? m4.y : 0;
        pos_s[t] = valid ? m4.z : 0;
    }
    __syncthreads();
    if (!val_s[0]) return;

    int r = 0;
#pragma unroll
    for (int i = 1; i < NRELS; i++) if (base >= offs[i]) r = i;

#pragma unroll
    for (int u = 0; u < 8; u++) {
        int v = u * 256 + t;
        int i = v >> 5;
        int c = v & 31;
        int node = (c < 16) ? dstn_s[i] : srcn_s[i];
        *(short8*)&Xs[i * XPITCH + c * 8] = *(const short8*)&h16[(size_t)node * DIM + (c & 15) * 8];
    }

    const int wave = t >> 6;
    const int lane = t & 63;
    const int q = lane >> 4;
    const int l16 = lane & 15;
    const int o16 = wave * 16 + l16;

    // in-loop B pointers (L2-hot tables)
    const unsigned short* bp0 = relT + ((size_t)r * DIM + (wave * 2 + 0) * 16 + l16) * TWOD + q * 8;
    const unsigned short* bp1 = relT + ((size_t)r * DIM + (wave * 2 + 1) * 16 + l16) * TWOD + q * 8;
    const unsigned short* wb  = Wa16 + (size_t)o16 * TWOD + q * 8;

    __syncthreads();

    floatx4 acc[4][2];
    floatx4 accS[4];
#pragma unroll
    for (int m = 0; m < 4; m++) {
        acc[m][0] = (floatx4)(0.0f);
        acc[m][1] = (floatx4)(0.0f);
        accS[m] = (floatx4)(0.0f);
    }

#pragma unroll
    for (int ks = 0; ks < 8; ks++) {
        short8 B0 = *(const short8*)(bp0 + ks * 32);
        short8 B1 = *(const short8*)(bp1 + ks * 32);
        short8 BS = *(const short8*)(wb + ks * 32);
        short8 Af[4];
        const unsigned short* xb = &Xs[l16 * XPITCH + ks * 32 + q * 8];
#pragma unroll
        for (int m = 0; m < 4; m++) Af[m] = *(const short8*)(xb + m * 16 * XPITCH);
#pragma unroll
        for (int m = 0; m < 4; m++) {
            acc[m][0] = __builtin_amdgcn_mfma_f32_16x16x32_bf16(Af[m], B0, acc[m][0], 0, 0, 0);
            acc[m][1] = __builtin_amdgcn_mfma_f32_16x16x32_bf16(Af[m], B1, acc[m][1], 0, 0, 0);
            accS[m]   = __builtin_amdgcn_mfma_f32_16x16x32_bf16(Af[m], BS, accS[m], 0, 0, 0);
        }
    }

    __syncthreads();  // all Xs reads done before overwriting dst half

    // score epilogue: leaky + ratt + 16-lane reduce, wave partials to LDS
    {
        float ba = b_a[o16];
        float ra = ratt[o16];
#pragma unroll
        for (int m = 0; m < 4; m++) {
#pragma unroll
            for (int rg = 0; rg < 4; rg++) {
                float v = accS[m][rg] + ba;
                v = v > 0.0f ? v : SLOPE * v;
                v *= ra;
#pragma unroll
                for (int off = 8; off > 0; off >>= 1) v += __shfl_xor(v, off, 16);
                if (l16 == 0) scoreW[m * 16 + q * 4 + rg][wave] = v;
            }
        }
    }

    // gate epilogue: msg = sigmoid(acc) * src_h -> Xs dst half (bf16)
#pragma unroll
    for (int m = 0; m < 4; m++) {
        int ib = m * 16 + q * 4;
#pragma unroll
        for (int nn = 0; nn < 2; nn++) {
            int o = (wave * 2 + nn) * 16 + l16;
#pragma unroll
            for (int rg = 0; rg < 4; rg++) {
                int i = ib + rg;
                float g = 1.0f / (1.0f + __expf(-acc[m][nn][rg]));
                float sh = bf2f(Xs[i * XPITCH + DIM + o]);
                Xs[i * XPITCH + o] = f2bf(sh * g);
            }
        }
    }
    __syncthreads();

#pragma unroll
    for (int u = 0; u < 4; u++) {
        int v = u * 256 + t;
        int i = v >> 4;
        int c = v & 15;
        if (!val_s[i]) continue;
        short8 val = *(const short8*)&Xs[i * XPITCH + c * 8];
        *(short8*)&msgbuf[(size_t)pos_s[i] * DIM + c * 8] = val;
    }
    if (t < EPB && val_s[t]) {
        scoreP[pos_s[t]] = scoreW[t][0] + scoreW[t][1] + scoreW[t][2] + scoreW[t][3];
    }
}

// ---------------- segment softmax, 16-lane groups ----------------
__global__ __launch_bounds__(256) void k_segsoft(float* __restrict__ scoreP,
                                                 const int* __restrict__ row_ptr) {
    int n = blockIdx.x * 16 + (threadIdx.x >> 4);
    int l = threadIdx.x & 15;
    if (n >= NNODES) return;
    int p0 = row_ptr[n], p1 = row_ptr[n + 1];
    if (p0 >= p1) return;
    float m = -3.0e38f;
    for (int p = p0 + l; p < p1; p += 16) m = fmaxf(m, scoreP[p]);
#pragma unroll
    for (int off = 8; off > 0; off >>= 1) m = fmaxf(m, __shfl_xor(m, off, 16));
    float sum = 0.0f;
    for (int p = p0 + l; p < p1; p += 16) {
        float x = __expf(scoreP[p] - m);
        scoreP[p] = x;
        sum += x;
    }
#pragma unroll
    for (int off = 8; off > 0; off >>= 1) sum += __shfl_xor(sum, off, 16);
    float inv = 1.0f / sum;
    for (int p = p0 + l; p < p1; p += 16) scoreP[p] *= inv;
}

// ---------------- segment-sum with attention -> hN bf16 ----------------
__global__ __launch_bounds__(256) void k_aggr(const unsigned short* __restrict__ msgbuf,
                                              const float* __restrict__ attP,
                                              const int* __restrict__ row_ptr,
                                              unsigned short* __restrict__ hN16) {
    int n = blockIdx.x * 4 + (threadIdx.x >> 6);
    int lane = threadIdx.x & 63;
    if (n >= NNODES) return;
    int p0 = row_ptr[n], p1 = row_ptr[n + 1];
    float a0 = 0.0f, a1 = 0.0f;
    for (int p = p0; p < p1; p++) {
        float at = attP[p];
        unsigned v = *(const unsigned*)&msgbuf[(size_t)p * DIM + lane * 2];
        a0 += at * bf2f((unsigned short)(v & 0xFFFFu));
        a1 += at * bf2f((unsigned short)(v >> 16));
    }
    unsigned o = (unsigned)f2bf(a0) | ((unsigned)f2bf(a1) << 16);
    *(unsigned*)&hN16[(size_t)n * DIM + lane * 2] = o;
}

// ---------------- out = leaky(W_lin @ [h ; h_N] + b) via MFMA ----------------
__global__ __launch_bounds__(256) void k_out(const unsigned short* __restrict__ h16,
                                             const unsigned short* __restrict__ hN16,
                                             const unsigned short* __restrict__ Wl,
                                             const float* __restrict__ b_lin,
                                             float* __restrict__ out) {
    __shared__ unsigned short Xs[EPB * XPITCH];
    const int t = threadIdx.x;
    const int nb = blockIdx.x * 64;

#pragma unroll
    for (int u = 0; u < 8; u++) {
        int v = u * 256 + t;
        int i = v >> 5;
        int c = v & 31;
        int n = nb + i;
        if (n >= NNODES) n = NNODES - 1;
        const unsigned short* srcp = (c < 16) ? h16 : hN16;
        *(short8*)&Xs[i * XPITCH + c * 8] = *(const short8*)&srcp[(size_t)n * DIM + (c & 15) * 8];
    }

    const int wave = t >> 6;
    const int lane = t & 63;
    const int q = lane >> 4;
    const int l16 = lane & 15;

    short8 Bf[2][8];
#pragma unroll
    for (int nn = 0; nn < 2; nn++) {
        int o = (wave * 2 + nn) * 16 + l16;
        const unsigned short* bp = Wl + (size_t)o * TWOD + q * 8;
#pragma unroll
        for (int ks = 0; ks < 8; ks++) Bf[nn][ks] = *(const short8*)(bp + ks * 32);
    }

    __syncthreads();

    floatx4 acc[4][2];
#pragma unroll
    for (int m = 0; m < 4; m++)
#pragma unroll
        for (int nn = 0; nn < 2; nn++) acc[m][nn] = (floatx4)(0.0f);

#pragma unroll
    for (int ks = 0; ks < 8; ks++) {
        short8 Af[4];
        const unsigned short* xb = &Xs[l16 * XPITCH + ks * 32 + q * 8];
#pragma unroll
        for (int m = 0; m < 4; m++) Af[m] = *(const short8*)(xb + m * 16 * XPITCH);
#pragma unroll
        for (int m = 0; m < 4; m++)
#pragma unroll
            for (int nn = 0; nn < 2; nn++)
                acc[m][nn] = __builtin_amdgcn_mfma_f32_16x16x32_bf16(Af[m], Bf[nn][ks], acc[m][nn], 0, 0, 0);
    }

#pragma unroll
    for (int m = 0; m < 4; m++) {
        int ib = m * 16 + q * 4;
#pragma unroll
        for (int nn = 0; nn < 2; nn++) {
            int o = (wave * 2 + nn) * 16 + l16;
            float bl = b_lin[o];
#pragma unroll
            for (int rg = 0; rg < 4; rg++) {
                int n = nb + ib + rg;
                if (n < NNODES) {
                    float val = acc[m][nn][rg] + bl;
                    val = val > 0.0f ? val : SLOPE * val;
                    out[(size_t)n * DIM + o] = val;
                }
            }
        }
    }
}

// ---------------- launcher ----------------
extern "C" void kernel_launch(void* const* d_in, const int* in_sizes, int n_in,
                              void* d_out, int out_size, void* d_ws, size_t ws_size,
                              hipStream_t stream) {
    const float* h     = (const float*)d_in[0];
    const float* rel   = (const float*)d_in[1];
    const float* ratt  = (const float*)d_in[2];
    const float* W_a   = (const float*)d_in[3];
    const float* b_a   = (const float*)d_in[4];
    const float* W_lin = (const float*)d_in[5];
    const float* b_lin = (const float*)d_in[6];
    const int* src = (const int*)d_in[7];
    const int* dst = (const int*)d_in[8];
    const int* ety = (const int*)d_in[9];
    float* out = (float*)d_out;

    // workspace layout (~173 MB)
    float* scoreP = (float*)d_ws;                                   // E
    unsigned short* h16  = (unsigned short*)(scoreP + NEDGES);      // N*128 bf16
    unsigned short* hN16 = h16 + (size_t)NNODES * DIM;              // N*128 bf16
    unsigned short* relT = hN16 + (size_t)NNODES * DIM;             // 8*128*256 bf16
    unsigned short* Wl   = relT + (size_t)NRELS * DIM * TWOD;       // 128*256 bf16
    unsigned short* Wa16 = Wl + (size_t)DIM * TWOD;                 // 64*256 bf16
    int4* meta4  = (int4*)(Wa16 + (size_t)ADIM * TWOD);             // E int4
    int4* sMeta  = meta4 + NEDGES;                                  // SPAD int4
    int* row_ptr = (int*)(sMeta + SPAD);                            // N+1
    int* histD   = row_ptr + (NNODES + 1);                          // N
    int* cursorD = histD + NNODES;                                  // N
    int* cnts    = cursorD + NNODES;                                // 16
    int* offs    = cnts + 16;                                       // 8
    unsigned short* msgbuf = (unsigned short*)(((uintptr_t)(offs + 8) + 255) & ~(uintptr_t)255); // E*128 bf16

    k_init<<<2048, 256, 0, stream>>>(sMeta, histD, cursorD, cnts);
    k_prep<<<64 + (DIM * TWOD + ADIM * TWOD + 255) / 256, 256, 0, stream>>>(
        rel, W_lin, W_a, relT, Wl, Wa16);
    k_h16<<<(NNODES * DIM / 8 + 255) / 256, 256, 0, stream>>>(h, h16);
    k_hist2<<<(NEDGES + 255) / 256, 256, 0, stream>>>(ety, dst, cnts, histD);
    k_scan<<<1, 1024, 0, stream>>>(histD, row_ptr, cnts, offs);
    k_dscatter<<<(NEDGES + 255) / 256, 256, 0, stream>>>(
        ety, src, dst, row_ptr, cursorD, meta4);
    k_scatter3<<<(NEDGES + 255) / 256, 256, 0, stream>>>(meta4, offs, cnts + 8, sMeta);
    k_gate_msg<<<(NEDGES + 8 * EPB + EPB - 1) / EPB, 256, 0, stream>>>(
        h16, relT, Wa16, sMeta, b_a, ratt, offs, msgbuf, scoreP);
    k_segsoft<<<(NNODES + 15) / 16, 256, 0, stream>>>(scoreP, row_ptr);
    k_aggr<<<(NNODES + 3) / 4, 256, 0, stream>>>(msgbuf, scoreP, row_ptr, hN16);
    k_out<<<(NNODES + 63) / 64, 256, 0, stream>>>(h16, hN16, Wl, b_lin, out);
}